// Round 1
// 2058.824 us; speedup vs baseline: 1.1342x; 1.1342x over previous
//
#include <hip/hip_runtime.h>
#include <hip/hip_bf16.h>
#include <math.h>

// Problem constants
#define NPB  192            // N*P = 32*6
#define CCH  128
#define TT   64
#define VV   25
#define PIX  1600           // T*V
#define SS   3
#define EPC  307200.0f      // elems per channel for BN (192*1600)
static const size_t ETOT = (size_t)NPB * CCH * PIX;   // 39,321,600

typedef __attribute__((ext_vector_type(4))) float f32x4;
typedef __attribute__((ext_vector_type(8))) short short8;

__device__ __forceinline__ ushort f2bf(float f) {
    __hip_bfloat16 h = __float2bfloat16(f);
    return __builtin_bit_cast(unsigned short, h);
}
__device__ __forceinline__ float bf2f(ushort u) {
    unsigned int x = ((unsigned int)u) << 16;
    return __builtin_bit_cast(float, x);
}

// ---------------------------------------------------------------------------
// Weight prep: permute w_in rows to [q0|k0|q1|k1|q2|k2] (64-chunks), cvt bf16
// ---------------------------------------------------------------------------
__global__ void wprep(const float* __restrict__ w_in, const float* __restrict__ b_in,
                      const float* __restrict__ w_out, const float* __restrict__ w_ff,
                      ushort* __restrict__ Wp, float* __restrict__ bp,
                      ushort* __restrict__ Wo, ushort* __restrict__ Wf) {
    int i = blockIdx.x * 256 + threadIdx.x;   // grid covers 49152
    if (i < 192 * 128) {
        int r = i >> 7, c = i & 127;
        int s = r / 64, j = r % 64;
        int src = (j < 32) ? (s * 32 + j) : (96 + s * 32 + (j - 32));
        Wp[i] = f2bf(w_in[src * 128 + c]);
        if (c == 0) bp[r] = b_in[src];
    }
    if (i < 128 * 384) Wo[i] = f2bf(w_out[i]);
    if (i < 128 * 128) Wf[i] = f2bf(w_ff[i]);
}

// ---------------------------------------------------------------------------
// remap: xr[np][c][v*64+t] = bf16(x[np][c][t*25+v])
// ---------------------------------------------------------------------------
__global__ void remap_x(const float* __restrict__ x, ushort* __restrict__ xr) {
    size_t o = ((size_t)blockIdx.x * 256 + threadIdx.x) * 4;
    size_t row = o / PIX;
    int p = (int)(o % PIX);           // v*64 + t0, t0 multiple of 4
    int v = p >> 6, t0 = p & 63;
    const float* xp = x + row * PIX;
    uint2 u;
    u.x = (uint)f2bf(xp[(t0 + 0) * 25 + v]) | ((uint)f2bf(xp[(t0 + 1) * 25 + v]) << 16);
    u.y = (uint)f2bf(xp[(t0 + 2) * 25 + v]) | ((uint)f2bf(xp[(t0 + 3) * 25 + v]) << 16);
    *(uint2*)(xr + o) = u;
}

// ---------------------------------------------------------------------------
// MFMA conv GEMM: out[np][obase+o][pix] (+)= sum_{k<128} W[o][k]*in[np][k][pix]
//  o-chunk 64 (blockIdx.z), pix tile 128 (blockIdx.y), K=128 in 2 chunks of 64
//  A = W (m=o), B = in (n=pix), 16x16x32 bf16 MFMA
// ---------------------------------------------------------------------------
__global__ __launch_bounds__(256)
void gemm_conv(const void* __restrict__ inp, int in_bf16,
               const ushort* __restrict__ W, int ldw,
               const float* __restrict__ bias,
               void* __restrict__ outp, int out_bf16, int out_ch,
               int accflag)
{
    __shared__ ushort Wt[64 * 72];
    __shared__ ushort Xt[128 * 72];
    const int np = blockIdx.x;
    const int pixbase = blockIdx.y * 128;
    const int obase = blockIdx.z * 64;
    const int tid = threadIdx.x;
    const int wave = tid >> 6, lane = tid & 63;
    const int quad = lane >> 4, l16 = lane & 15;
    const int wPix = wave * 32;

    f32x4 acc[4][2];
    if (accflag) {
        const float* op = (const float*)outp + ((size_t)np * out_ch + obase) * PIX + pixbase;
#pragma unroll
        for (int ms = 0; ms < 4; ++ms)
#pragma unroll
            for (int ns = 0; ns < 2; ++ns) {
                int pl = wPix + ns * 16 + l16;
                bool valid = (pixbase + pl) < PIX;
#pragma unroll
                for (int r = 0; r < 4; ++r) {
                    int ol = ms * 16 + quad * 4 + r;
                    acc[ms][ns][r] = valid ? op[(size_t)ol * PIX + pl] : 0.f;
                }
            }
    } else {
#pragma unroll
        for (int ms = 0; ms < 4; ++ms) {
            float bv[4];
#pragma unroll
            for (int r = 0; r < 4; ++r) {
                int ol = ms * 16 + quad * 4 + r;
                bv[r] = bias ? bias[obase + ol] : 0.f;
            }
#pragma unroll
            for (int ns = 0; ns < 2; ++ns)
#pragma unroll
                for (int r = 0; r < 4; ++r) acc[ms][ns][r] = bv[r];
        }
    }

    const ushort* inb = (const ushort*)inp;
    const float* inf = (const float*)inp;
    const size_t in_off = (size_t)np * 128 * PIX;

    for (int kc = 0; kc < 2; ++kc) {
        const int kbase = kc * 64;
        // ---- stage Wt[o][k] (64x64 bf16), rows padded to 72
        {
            int o = tid >> 2, seg = tid & 3;
            const ushort* src = W + (size_t)(obase + o) * ldw + kbase + seg * 16;
            uint4 a = *(const uint4*)src;
            uint4 b = *(const uint4*)(src + 8);
            *(uint4*)&Wt[o * 72 + seg * 16] = a;
            *(uint4*)&Wt[o * 72 + seg * 16 + 8] = b;
        }
        // ---- stage Xt[p][k] transposed (128 pix x 64 k), b32-packed writes
        {
            int cp = tid & 31, rq = tid >> 5;
            int c = cp * 2;
            int p0 = rq * 16;
            bool valid = (pixbase + p0) < PIX;
            if (in_bf16) {
                uint ra[8], rb[8];
                if (valid) {
                    const ushort* s0 = inb + in_off + (size_t)(kbase + c) * PIX + pixbase + p0;
                    const ushort* s1 = s0 + PIX;
                    *(uint4*)&ra[0] = *(const uint4*)s0;
                    *(uint4*)&ra[4] = *(const uint4*)(s0 + 8);
                    *(uint4*)&rb[0] = *(const uint4*)s1;
                    *(uint4*)&rb[4] = *(const uint4*)(s1 + 8);
                } else {
#pragma unroll
                    for (int h = 0; h < 8; ++h) { ra[h] = 0; rb[h] = 0; }
                }
#pragma unroll
                for (int h = 0; h < 8; ++h) {
                    uint lo = ra[h], hi = rb[h];
                    *(uint*)&Xt[(p0 + 2 * h) * 72 + c] = (lo & 0xffffu) | (hi << 16);
                    *(uint*)&Xt[(p0 + 2 * h + 1) * 72 + c] = (lo >> 16) | (hi & 0xffff0000u);
                }
            } else {
                if (valid) {
                    const float* s0 = inf + in_off + (size_t)(kbase + c) * PIX + pixbase + p0;
                    const float* s1 = s0 + PIX;
#pragma unroll
                    for (int b4 = 0; b4 < 4; ++b4) {
                        float4 u = ((const float4*)s0)[b4];
                        float4 w4 = ((const float4*)s1)[b4];
                        int p = p0 + b4 * 4;
                        *(uint*)&Xt[(p + 0) * 72 + c] = (uint)f2bf(u.x) | ((uint)f2bf(w4.x) << 16);
                        *(uint*)&Xt[(p + 1) * 72 + c] = (uint)f2bf(u.y) | ((uint)f2bf(w4.y) << 16);
                        *(uint*)&Xt[(p + 2) * 72 + c] = (uint)f2bf(u.z) | ((uint)f2bf(w4.z) << 16);
                        *(uint*)&Xt[(p + 3) * 72 + c] = (uint)f2bf(u.w) | ((uint)f2bf(w4.w) << 16);
                    }
                } else {
#pragma unroll
                    for (int h = 0; h < 16; ++h) *(uint*)&Xt[(p0 + h) * 72 + c] = 0;
                }
            }
        }
        __syncthreads();
        // ---- compute: 2 k-steps of 32
#pragma unroll
        for (int ks = 0; ks < 2; ++ks) {
            const int kk = ks * 32;
            short8 a[4], b[2];
#pragma unroll
            for (int ms = 0; ms < 4; ++ms)
                a[ms] = *(const short8*)&Wt[(ms * 16 + l16) * 72 + kk + quad * 8];
#pragma unroll
            for (int ns = 0; ns < 2; ++ns)
                b[ns] = *(const short8*)&Xt[(wPix + ns * 16 + l16) * 72 + kk + quad * 8];
#pragma unroll
            for (int ms = 0; ms < 4; ++ms)
#pragma unroll
                for (int ns = 0; ns < 2; ++ns)
                    acc[ms][ns] = __builtin_amdgcn_mfma_f32_16x16x32_bf16(a[ms], b[ns], acc[ms][ns], 0, 0, 0);
        }
        __syncthreads();
    }

    // ---- epilogue
    if (out_bf16) {
        ushort* op = (ushort*)outp + ((size_t)np * out_ch + obase) * PIX + pixbase;
#pragma unroll
        for (int ms = 0; ms < 4; ++ms)
#pragma unroll
            for (int ns = 0; ns < 2; ++ns) {
                int pl = wPix + ns * 16 + l16;
                if (pixbase + pl >= PIX) continue;
#pragma unroll
                for (int r = 0; r < 4; ++r) {
                    int ol = ms * 16 + quad * 4 + r;
                    op[(size_t)ol * PIX + pl] = f2bf(acc[ms][ns][r]);
                }
            }
    } else {
        float* op = (float*)outp + ((size_t)np * out_ch + obase) * PIX + pixbase;
#pragma unroll
        for (int ms = 0; ms < 4; ++ms)
#pragma unroll
            for (int ns = 0; ns < 2; ++ns) {
                int pl = wPix + ns * 16 + l16;
                if (pixbase + pl >= PIX) continue;
#pragma unroll
                for (int r = 0; r < 4; ++r) {
                    int ol = ms * 16 + quad * 4 + r;
                    op[(size_t)ol * PIX + pl] = acc[ms][ns][r];
                }
            }
    }
}

// ---------------------------------------------------------------------------
// scores via MFMA: att[n,s,p,t,q] = attb + tanh( (Q·K)/800 )*alpha
//  Per block (np,s): 64x64 output, contraction k=(ci,v) zero-padded to 32/ci.
//  LDS layout: Qs/Ks [row(64)][k(128)] bf16, 16B-block XOR swizzle blk^=(row&7).
//  8 chunks of 4 channels (k-chunk 128 = 4ci x 32v'), 4 waves = 2x2 quadrants.
// ---------------------------------------------------------------------------
__global__ __launch_bounds__(256)
void scores_mfma(const ushort* __restrict__ qk, const float* __restrict__ attb,
                 const float* __restrict__ alphat, float* __restrict__ att)
{
    __shared__ ushort Qs[64 * 128];
    __shared__ ushort Ks[64 * 128];
    const int np = blockIdx.x, s = blockIdx.y, tid = threadIdx.x;
    const int wave = tid >> 6, lane = tid & 63;
    const int quad = lane >> 4, l16 = lane & 15;
    const int tH = (wave >> 1) * 32, qH = (wave & 1) * 32;
    const ushort* qb = qk + ((size_t)np * 192 + s * 64) * PIX;
    const ushort* kb = qb + (size_t)32 * PIX;

    // staging role: waves 0,1 -> Q side, waves 2,3 -> K side; each lane owns
    // one (ci-of-4, t-pair) row pair per chunk.
    const int side = wave >> 1;
    const int cil = (wave & 1) * 2 + (lane >> 5);   // 0..3 within chunk
    const int t0 = (lane & 31) * 2;
    const ushort* sbase = (side ? kb : qb);
    ushort* dst = side ? Ks : Qs;

    f32x4 acc[2][2];
#pragma unroll
    for (int ms = 0; ms < 2; ++ms)
#pragma unroll
        for (int ns = 0; ns < 2; ++ns)
#pragma unroll
            for (int r = 0; r < 4; ++r) acc[ms][ns][r] = 0.f;

    for (int c = 0; c < 8; ++c) {
        __syncthreads();
        // ---- stage 4 channels of Q and K, transposed to [t][k], swizzled
        {
            const int ci = c * 4 + cil;
            const ushort* sb = sbase + (size_t)ci * PIX + t0;
            uint u[25];
#pragma unroll
            for (int v = 0; v < 25; ++v)
                u[v] = *(const uint*)(sb + v * 64);
            uint rA[16], rB[16];
#pragma unroll
            for (int w2 = 0; w2 < 12; ++w2) {
                uint a = u[2 * w2], b = u[2 * w2 + 1];
                rA[w2] = (a & 0xffffu) | (b << 16);
                rB[w2] = (a >> 16) | (b & 0xffff0000u);
            }
            rA[12] = u[24] & 0xffffu;  rB[12] = u[24] >> 16;
            rA[13] = 0u; rA[14] = 0u; rA[15] = 0u;
            rB[13] = 0u; rB[14] = 0u; rB[15] = 0u;
#pragma unroll
            for (int b4 = 0; b4 < 4; ++b4) {
                int blkA = (cil * 4 + b4) ^ (t0 & 7);
                int blkB = (cil * 4 + b4) ^ ((t0 + 1) & 7);
                uint4 wa, wb;
                wa.x = rA[b4 * 4 + 0]; wa.y = rA[b4 * 4 + 1];
                wa.z = rA[b4 * 4 + 2]; wa.w = rA[b4 * 4 + 3];
                wb.x = rB[b4 * 4 + 0]; wb.y = rB[b4 * 4 + 1];
                wb.z = rB[b4 * 4 + 2]; wb.w = rB[b4 * 4 + 3];
                *(uint4*)&dst[t0 * 128 + blkA * 8] = wa;
                *(uint4*)&dst[(t0 + 1) * 128 + blkB * 8] = wb;
            }
        }
        __syncthreads();
        // ---- compute: 4 k-steps of 32 (k = ci*32 + v', v'>=25 zero)
#pragma unroll
        for (int ks = 0; ks < 4; ++ks) {
            short8 a[2], b[2];
#pragma unroll
            for (int ms = 0; ms < 2; ++ms) {
                int t = tH + ms * 16 + l16;
                int blk = (ks * 4 + quad) ^ (t & 7);
                a[ms] = *(const short8*)&Qs[t * 128 + blk * 8];
            }
#pragma unroll
            for (int ns = 0; ns < 2; ++ns) {
                int q = qH + ns * 16 + l16;
                int blk = (ks * 4 + quad) ^ (q & 7);
                b[ns] = *(const short8*)&Ks[q * 128 + blk * 8];
            }
#pragma unroll
            for (int ms = 0; ms < 2; ++ms)
#pragma unroll
                for (int ns = 0; ns < 2; ++ns)
                    acc[ms][ns] = __builtin_amdgcn_mfma_f32_16x16x32_bf16(a[ms], b[ns], acc[ms][ns], 0, 0, 0);
        }
    }

    // ---- epilogue: att = attb + tanh(acc/800)*alpha
    const float alpha = alphat[s];
    const int n = np / 6, p = np % 6;
    const float* bp2 = attb + (size_t)s * 4096;
    float* ap = att + ((size_t)(n * SS + s) * 6 + p) * 4096;
    const float inv = 1.0f / 800.0f;
#pragma unroll
    for (int ms = 0; ms < 2; ++ms)
#pragma unroll
        for (int ns = 0; ns < 2; ++ns) {
            int q = qH + ns * 16 + l16;
#pragma unroll
            for (int r = 0; r < 4; ++r) {
                int t = tH + ms * 16 + quad * 4 + r;
                ap[t * 64 + q] = bp2[t * 64 + q] + tanhf(acc[ms][ns][r] * inv) * alpha;
            }
        }
}

// ---------------------------------------------------------------------------
// attn MFMA: y[np][c][v*64+q] = sum_t xr[np][c][v*64+t] * att[t][q]  (bf16 out)
// ---------------------------------------------------------------------------
__global__ __launch_bounds__(256)
void attn_mm(const ushort* __restrict__ xr, const float* __restrict__ att,
             ushort* __restrict__ y, int s)
{
    __shared__ ushort Xa[128 * 72];
    __shared__ ushort Ta[64 * 72];
    const int np = blockIdx.x, v = blockIdx.y, tid = threadIdx.x;
    const int wave = tid >> 6, lane = tid & 63;
    const int quad = lane >> 4, l16 = lane & 15;
    const int cH = (wave & 1) * 64, qH = (wave >> 1) * 32;
    const int n = np / 6, p = np % 6;
    // stage Xa[c][t]: direct coalesced from xr
    {
        int c = tid >> 1, half = tid & 1;
        const ushort* src = xr + ((size_t)np * 128 + c) * PIX + v * 64 + half * 32;
        uint4 a = *(const uint4*)src;
        uint4 b = *(const uint4*)(src + 8);
        uint4 c0 = *(const uint4*)(src + 16);
        uint4 d = *(const uint4*)(src + 24);
        *(uint4*)&Xa[c * 72 + half * 32] = a;
        *(uint4*)&Xa[c * 72 + half * 32 + 8] = b;
        *(uint4*)&Xa[c * 72 + half * 32 + 16] = c0;
        *(uint4*)&Xa[c * 72 + half * 32 + 24] = d;
    }
    // stage Ta[q][t] = att[t][q] (bf16, b32-packed)
    {
        int q = tid >> 2, seg = tid & 3;
        const float* ab = att + ((size_t)(n * SS + s) * 6 + p) * 4096;
#pragma unroll
        for (int i2 = 0; i2 < 8; ++i2) {
            int t0 = seg * 16 + i2 * 2;
            uint w = (uint)f2bf(ab[t0 * 64 + q]) | ((uint)f2bf(ab[(t0 + 1) * 64 + q]) << 16);
            *(uint*)&Ta[q * 72 + t0] = w;
        }
    }
    __syncthreads();
    f32x4 acc[4][2];
#pragma unroll
    for (int ms = 0; ms < 4; ++ms)
#pragma unroll
        for (int ns = 0; ns < 2; ++ns)
#pragma unroll
            for (int r = 0; r < 4; ++r) acc[ms][ns][r] = 0.f;
#pragma unroll
    for (int ks = 0; ks < 2; ++ks) {
        const int kk = ks * 32;
        short8 a[4], b[2];
#pragma unroll
        for (int ms = 0; ms < 4; ++ms)
            a[ms] = *(const short8*)&Xa[(cH + ms * 16 + l16) * 72 + kk + quad * 8];
#pragma unroll
        for (int ns = 0; ns < 2; ++ns)
            b[ns] = *(const short8*)&Ta[(qH + ns * 16 + l16) * 72 + kk + quad * 8];
#pragma unroll
        for (int ms = 0; ms < 4; ++ms)
#pragma unroll
            for (int ns = 0; ns < 2; ++ns)
                acc[ms][ns] = __builtin_amdgcn_mfma_f32_16x16x32_bf16(a[ms], b[ns], acc[ms][ns], 0, 0, 0);
    }
    ushort* yp = y + (size_t)np * 128 * PIX + v * 64;
#pragma unroll
    for (int ms = 0; ms < 4; ++ms)
#pragma unroll
        for (int ns = 0; ns < 2; ++ns) {
            int q = qH + ns * 16 + l16;
#pragma unroll
            for (int r = 0; r < 4; ++r) {
                int c = cH + ms * 16 + quad * 4 + r;
                yp[(size_t)c * PIX + q] = f2bf(acc[ms][ns][r]);
            }
        }
}

// ---------------------------------------------------------------------------
// BN stats + finalize
// ---------------------------------------------------------------------------
__global__ void bn_stats(const float* __restrict__ z, float* __restrict__ stats) {
    const int c = blockIdx.x, np = blockIdx.y, tid = threadIdx.x;
    const float* zp = z + ((size_t)np * CCH + c) * PIX;
    float s = 0.f, s2 = 0.f;
    for (int i = tid; i < PIX; i += 256) {
        float v = zp[i];
        s += v; s2 += v * v;
    }
    for (int off = 32; off; off >>= 1) {
        s += __shfl_down(s, off);
        s2 += __shfl_down(s2, off);
    }
    __shared__ float ls[4], ls2[4];
    const int w = tid >> 6, lane = tid & 63;
    if (lane == 0) { ls[w] = s; ls2[w] = s2; }
    __syncthreads();
    if (tid == 0) {
        s = ls[0] + ls[1] + ls[2] + ls[3];
        s2 = ls2[0] + ls2[1] + ls2[2] + ls2[3];
        atomicAdd(&stats[c], s);
        atomicAdd(&stats[128 + c], s2);
    }
}

__global__ void bn_finalize(const float* __restrict__ stats, const float* __restrict__ g,
                            const float* __restrict__ be, float* __restrict__ scsh) {
    const int c = threadIdx.x;
    float mean = stats[c] * (1.0f / EPC);
    float var = stats[128 + c] * (1.0f / EPC) - mean * mean;
    float inv = rsqrtf(var + 1e-5f);
    float sc = g[c] * inv;
    scsh[c] = sc;
    scsh[128 + c] = be[c] - mean * sc;
}

// ---------------------------------------------------------------------------
// res1: y1[i(orig)] = leaky(x[i] + bn(Z'[perm(i)]))   (Z' in pix' order)
// ---------------------------------------------------------------------------
__global__ void res_bn_g(const float* __restrict__ x, const float* __restrict__ z,
                         const float* __restrict__ scsh, float* __restrict__ out) {
    size_t i = ((size_t)blockIdx.x * 256 + threadIdx.x) * 4;
    size_t row = i / PIX;
    int p = (int)(i % PIX);
    int ch = (int)(row & 127);
    float sc = scsh[ch], sh = scsh[128 + ch];
    const float* zr = z + row * PIX;
    float4 a = *(const float4*)(x + i);
    float xin[4] = {a.x, a.y, a.z, a.w};
    float4 r;
    float ro[4];
#pragma unroll
    for (int j = 0; j < 4; ++j) {
        int pp = p + j;
        int t = pp / 25, vv = pp - t * 25;
        float zz = zr[vv * 64 + t];
        float val = xin[j] + fmaf(zz, sc, sh);
        ro[j] = val >= 0.f ? val : 0.1f * val;
    }
    r.x = ro[0]; r.y = ro[1]; r.z = ro[2]; r.w = ro[3];
    *(float4*)(out + i) = r;
}

// ---------------------------------------------------------------------------
// res2: out = leaky(y1 + bn(z2)), all orig order, float4
// ---------------------------------------------------------------------------
__global__ void res_bn_l(const float4* __restrict__ xr, const float4* __restrict__ zr,
                         const float* __restrict__ scsh, float4* __restrict__ out) {
    int i = blockIdx.x * 256 + threadIdx.x;
    int row = i / 400;
    int ch = row & 127;
    float sc = scsh[ch], sh = scsh[128 + ch];
    float4 a = xr[i], b = zr[i], r;
    r.x = a.x + fmaf(b.x, sc, sh);
    r.y = a.y + fmaf(b.y, sc, sh);
    r.z = a.z + fmaf(b.z, sc, sh);
    r.w = a.w + fmaf(b.w, sc, sh);
    r.x = r.x >= 0.f ? r.x : 0.1f * r.x;
    r.y = r.y >= 0.f ? r.y : 0.1f * r.y;
    r.z = r.z >= 0.f ? r.z : 0.1f * r.z;
    r.w = r.w >= 0.f ? r.w : 0.1f * r.w;
    out[i] = r;
}

// ---------------------------------------------------------------------------
struct Ctx {
    ushort *xr, *Wp, *Wo, *Wf;
    float *bp;
    float *R1, *R0, *ATT, *STATS;
    const float *alphat, *b_out, *g_out, *be_out, *b_ff, *g_ff, *be_ff;
};

static void run_block(const float* X, const float* attb, float* OUT,
                      const Ctx& c, hipStream_t stream) {
    const int EG = 38400;   // 39,321,600 / (256*4)
    remap_x<<<EG, 256, 0, stream>>>(X, c.xr);
    // q/k conv -> QK (bf16, in R1), channels [q0|k0|q1|k1|q2|k2]
    gemm_conv<<<dim3(NPB, 13, 3), 256, 0, stream>>>(c.xr, 1, c.Wp, 128, c.bp,
                                                    (void*)c.R1, 1, 192, 0);
    scores_mfma<<<dim3(NPB, 3), 256, 0, stream>>>((const ushort*)c.R1, attb, c.alphat, c.ATT);
    // per-s: attention apply (bf16 y in R1) then accumulate conv_out into Z (R0)
    for (int s = 0; s < SS; ++s) {
        attn_mm<<<dim3(NPB, VV), 256, 0, stream>>>(c.xr, c.ATT, (ushort*)c.R1, s);
        gemm_conv<<<dim3(NPB, 13, 2), 256, 0, stream>>>((const ushort*)c.R1, 1,
                                                        c.Wo + s * 128, 384,
                                                        (s == 0) ? c.b_out : nullptr,
                                                        (void*)c.R0, 0, 128, s != 0);
    }
    hipMemsetAsync(c.STATS, 0, 256 * sizeof(float), stream);
    bn_stats<<<dim3(CCH, NPB), 256, 0, stream>>>(c.R0, c.STATS);
    bn_finalize<<<1, 128, 0, stream>>>(c.STATS, c.g_out, c.be_out, c.STATS + 256);
    res_bn_g<<<EG, 256, 0, stream>>>(X, c.R0, c.STATS + 256, c.R1);   // y1 fp32 in R1
    gemm_conv<<<dim3(NPB, 13, 2), 256, 0, stream>>>(c.R1, 0, c.Wf, 128, c.b_ff,
                                                    (void*)c.R0, 0, 128, 0);  // z2 in R0
    hipMemsetAsync(c.STATS, 0, 256 * sizeof(float), stream);
    bn_stats<<<dim3(CCH, NPB), 256, 0, stream>>>(c.R0, c.STATS);
    bn_finalize<<<1, 128, 0, stream>>>(c.STATS, c.g_ff, c.be_ff, c.STATS + 256);
    res_bn_l<<<EG, 256, 0, stream>>>((const float4*)c.R1, (const float4*)c.R0,
                                     c.STATS + 256, (float4*)OUT);
}

extern "C" void kernel_launch(void* const* d_in, const int* in_sizes, int n_in,
                              void* d_out, int out_size, void* d_ws, size_t ws_size,
                              hipStream_t stream) {
    const float* x = (const float*)d_in[0];
    const float* att1 = (const float*)d_in[1];
    const float* att2 = (const float*)d_in[2];
    Ctx c;
    c.alphat = (const float*)d_in[3];
    const float* w_in = (const float*)d_in[4];
    const float* b_in = (const float*)d_in[5];
    const float* w_out = (const float*)d_in[6];
    c.b_out = (const float*)d_in[7];
    c.g_out = (const float*)d_in[8];
    c.be_out = (const float*)d_in[9];
    const float* w_ff = (const float*)d_in[10];
    c.b_ff = (const float*)d_in[11];
    c.g_ff = (const float*)d_in[12];
    c.be_ff = (const float*)d_in[13];

    char* ws = (char*)d_ws;
    size_t off = 0;
    c.xr = (ushort*)(ws + off);   off += ETOT * 2;                    //  78.6 MB
    c.R1 = (float*)(ws + off);    off += ETOT * 4;                    // 157.3 MB
    c.R0 = (float*)(ws + off);    off += ETOT * 4;                    // 157.3 MB
    c.ATT = (float*)(ws + off);   off += (size_t)32 * 3 * 6 * 4096 * 4; // 9.4 MB
    c.STATS = (float*)(ws + off); off += 512 * 4;
    c.Wp = (ushort*)(ws + off);   off += 192 * 128 * 2;
    c.bp = (float*)(ws + off);    off += 192 * 4;
    c.Wo = (ushort*)(ws + off);   off += 128 * 384 * 2;
    c.Wf = (ushort*)(ws + off);   off += 128 * 128 * 2;

    wprep<<<192, 256, 0, stream>>>(w_in, b_in, w_out, w_ff, c.Wp, c.bp, c.Wo, c.Wf);

    float* out = (float*)d_out;
    run_block(x, att1, out, c, stream);
    run_block(out, att2, out, c, stream);
}

// Round 2
// 1663.477 us; speedup vs baseline: 1.4038x; 1.2377x over previous
//
#include <hip/hip_runtime.h>
#include <hip/hip_bf16.h>
#include <math.h>

// Problem constants
#define NPB  192            // N*P = 32*6
#define CCH  128
#define TT   64
#define VV   25
#define PIX  1600           // T*V
#define SS   3
#define EPC  307200.0f      // elems per channel for BN (192*1600)
static const size_t ETOT = (size_t)NPB * CCH * PIX;   // 39,321,600

typedef __attribute__((ext_vector_type(4))) float f32x4;
typedef __attribute__((ext_vector_type(8))) short short8;

__device__ __forceinline__ ushort f2bf(float f) {
    __hip_bfloat16 h = __float2bfloat16(f);
    return __builtin_bit_cast(unsigned short, h);
}
__device__ __forceinline__ float bf2f(ushort u) {
    unsigned int x = ((unsigned int)u) << 16;
    return __builtin_bit_cast(float, x);
}

// ---------------------------------------------------------------------------
// Weight prep: permute w_in rows to [q0|k0|q1|k1|q2|k2] (64-chunks), cvt bf16
// ---------------------------------------------------------------------------
__global__ void wprep(const float* __restrict__ w_in, const float* __restrict__ b_in,
                      const float* __restrict__ w_out, const float* __restrict__ w_ff,
                      ushort* __restrict__ Wp, float* __restrict__ bp,
                      ushort* __restrict__ Wo, ushort* __restrict__ Wf) {
    int i = blockIdx.x * 256 + threadIdx.x;   // grid covers 49152
    if (i < 192 * 128) {
        int r = i >> 7, c = i & 127;
        int s = r / 64, j = r % 64;
        int src = (j < 32) ? (s * 32 + j) : (96 + s * 32 + (j - 32));
        Wp[i] = f2bf(w_in[src * 128 + c]);
        if (c == 0) bp[r] = b_in[src];
    }
    if (i < 128 * 384) Wo[i] = f2bf(w_out[i]);
    if (i < 128 * 128) Wf[i] = f2bf(w_ff[i]);
}

// ---------------------------------------------------------------------------
// remap: xr[np][c][v*64+t] = bf16(x[np][c][t*25+v])
// ---------------------------------------------------------------------------
__global__ void remap_x(const float* __restrict__ x, ushort* __restrict__ xr) {
    size_t o = ((size_t)blockIdx.x * 256 + threadIdx.x) * 4;
    size_t row = o / PIX;
    int p = (int)(o % PIX);           // v*64 + t0, t0 multiple of 4
    int v = p >> 6, t0 = p & 63;
    const float* xp = x + row * PIX;
    uint2 u;
    u.x = (uint)f2bf(xp[(t0 + 0) * 25 + v]) | ((uint)f2bf(xp[(t0 + 1) * 25 + v]) << 16);
    u.y = (uint)f2bf(xp[(t0 + 2) * 25 + v]) | ((uint)f2bf(xp[(t0 + 3) * 25 + v]) << 16);
    *(uint2*)(xr + o) = u;
}

// ---------------------------------------------------------------------------
// MFMA conv GEMM: out[np][obase+o][pix] (+)= sum_{k<128} W[o][k]*in[np][k][pix]
//  o-chunk 64 (blockIdx.z), pix tile 128 (blockIdx.y), K=128 in 2 chunks of 64
//  A = W (m=o), B = in (n=pix), 16x16x32 bf16 MFMA
// ---------------------------------------------------------------------------
__global__ __launch_bounds__(256)
void gemm_conv(const void* __restrict__ inp, int in_bf16,
               const ushort* __restrict__ W, int ldw,
               const float* __restrict__ bias,
               void* __restrict__ outp, int out_bf16, int out_ch,
               int accflag)
{
    __shared__ ushort Wt[64 * 72];
    __shared__ ushort Xt[128 * 72];
    const int np = blockIdx.x;
    const int pixbase = blockIdx.y * 128;
    const int obase = blockIdx.z * 64;
    const int tid = threadIdx.x;
    const int wave = tid >> 6, lane = tid & 63;
    const int quad = lane >> 4, l16 = lane & 15;
    const int wPix = wave * 32;

    f32x4 acc[4][2];
    if (accflag) {
        const float* op = (const float*)outp + ((size_t)np * out_ch + obase) * PIX + pixbase;
#pragma unroll
        for (int ms = 0; ms < 4; ++ms)
#pragma unroll
            for (int ns = 0; ns < 2; ++ns) {
                int pl = wPix + ns * 16 + l16;
                bool valid = (pixbase + pl) < PIX;
#pragma unroll
                for (int r = 0; r < 4; ++r) {
                    int ol = ms * 16 + quad * 4 + r;
                    acc[ms][ns][r] = valid ? op[(size_t)ol * PIX + pl] : 0.f;
                }
            }
    } else {
#pragma unroll
        for (int ms = 0; ms < 4; ++ms) {
            float bv[4];
#pragma unroll
            for (int r = 0; r < 4; ++r) {
                int ol = ms * 16 + quad * 4 + r;
                bv[r] = bias ? bias[obase + ol] : 0.f;
            }
#pragma unroll
            for (int ns = 0; ns < 2; ++ns)
#pragma unroll
                for (int r = 0; r < 4; ++r) acc[ms][ns][r] = bv[r];
        }
    }

    const ushort* inb = (const ushort*)inp;
    const float* inf = (const float*)inp;
    const size_t in_off = (size_t)np * 128 * PIX;

    for (int kc = 0; kc < 2; ++kc) {
        const int kbase = kc * 64;
        // ---- stage Wt[o][k] (64x64 bf16), rows padded to 72
        {
            int o = tid >> 2, seg = tid & 3;
            const ushort* src = W + (size_t)(obase + o) * ldw + kbase + seg * 16;
            uint4 a = *(const uint4*)src;
            uint4 b = *(const uint4*)(src + 8);
            *(uint4*)&Wt[o * 72 + seg * 16] = a;
            *(uint4*)&Wt[o * 72 + seg * 16 + 8] = b;
        }
        // ---- stage Xt[p][k] transposed (128 pix x 64 k), b32-packed writes
        {
            int cp = tid & 31, rq = tid >> 5;
            int c = cp * 2;
            int p0 = rq * 16;
            bool valid = (pixbase + p0) < PIX;
            if (in_bf16) {
                uint ra[8], rb[8];
                if (valid) {
                    const ushort* s0 = inb + in_off + (size_t)(kbase + c) * PIX + pixbase + p0;
                    const ushort* s1 = s0 + PIX;
                    *(uint4*)&ra[0] = *(const uint4*)s0;
                    *(uint4*)&ra[4] = *(const uint4*)(s0 + 8);
                    *(uint4*)&rb[0] = *(const uint4*)s1;
                    *(uint4*)&rb[4] = *(const uint4*)(s1 + 8);
                } else {
#pragma unroll
                    for (int h = 0; h < 8; ++h) { ra[h] = 0; rb[h] = 0; }
                }
#pragma unroll
                for (int h = 0; h < 8; ++h) {
                    uint lo = ra[h], hi = rb[h];
                    *(uint*)&Xt[(p0 + 2 * h) * 72 + c] = (lo & 0xffffu) | (hi << 16);
                    *(uint*)&Xt[(p0 + 2 * h + 1) * 72 + c] = (lo >> 16) | (hi & 0xffff0000u);
                }
            } else {
                if (valid) {
                    const float* s0 = inf + in_off + (size_t)(kbase + c) * PIX + pixbase + p0;
                    const float* s1 = s0 + PIX;
#pragma unroll
                    for (int b4 = 0; b4 < 4; ++b4) {
                        float4 u = ((const float4*)s0)[b4];
                        float4 w4 = ((const float4*)s1)[b4];
                        int p = p0 + b4 * 4;
                        *(uint*)&Xt[(p + 0) * 72 + c] = (uint)f2bf(u.x) | ((uint)f2bf(w4.x) << 16);
                        *(uint*)&Xt[(p + 1) * 72 + c] = (uint)f2bf(u.y) | ((uint)f2bf(w4.y) << 16);
                        *(uint*)&Xt[(p + 2) * 72 + c] = (uint)f2bf(u.z) | ((uint)f2bf(w4.z) << 16);
                        *(uint*)&Xt[(p + 3) * 72 + c] = (uint)f2bf(u.w) | ((uint)f2bf(w4.w) << 16);
                    }
                } else {
#pragma unroll
                    for (int h = 0; h < 16; ++h) *(uint*)&Xt[(p0 + h) * 72 + c] = 0;
                }
            }
        }
        __syncthreads();
        // ---- compute: 2 k-steps of 32
#pragma unroll
        for (int ks = 0; ks < 2; ++ks) {
            const int kk = ks * 32;
            short8 a[4], b[2];
#pragma unroll
            for (int ms = 0; ms < 4; ++ms)
                a[ms] = *(const short8*)&Wt[(ms * 16 + l16) * 72 + kk + quad * 8];
#pragma unroll
            for (int ns = 0; ns < 2; ++ns)
                b[ns] = *(const short8*)&Xt[(wPix + ns * 16 + l16) * 72 + kk + quad * 8];
#pragma unroll
            for (int ms = 0; ms < 4; ++ms)
#pragma unroll
                for (int ns = 0; ns < 2; ++ns)
                    acc[ms][ns] = __builtin_amdgcn_mfma_f32_16x16x32_bf16(a[ms], b[ns], acc[ms][ns], 0, 0, 0);
        }
        __syncthreads();
    }

    // ---- epilogue
    if (out_bf16) {
        ushort* op = (ushort*)outp + ((size_t)np * out_ch + obase) * PIX + pixbase;
#pragma unroll
        for (int ms = 0; ms < 4; ++ms)
#pragma unroll
            for (int ns = 0; ns < 2; ++ns) {
                int pl = wPix + ns * 16 + l16;
                if (pixbase + pl >= PIX) continue;
#pragma unroll
                for (int r = 0; r < 4; ++r) {
                    int ol = ms * 16 + quad * 4 + r;
                    op[(size_t)ol * PIX + pl] = f2bf(acc[ms][ns][r]);
                }
            }
    } else {
        float* op = (float*)outp + ((size_t)np * out_ch + obase) * PIX + pixbase;
#pragma unroll
        for (int ms = 0; ms < 4; ++ms)
#pragma unroll
            for (int ns = 0; ns < 2; ++ns) {
                int pl = wPix + ns * 16 + l16;
                if (pixbase + pl >= PIX) continue;
#pragma unroll
                for (int r = 0; r < 4; ++r) {
                    int ol = ms * 16 + quad * 4 + r;
                    op[(size_t)ol * PIX + pl] = acc[ms][ns][r];
                }
            }
    }
}

// ---------------------------------------------------------------------------
// scores via MFMA: att[n,s,p,t,q] = attb + tanh( (Q·K)/800 )*alpha
// ---------------------------------------------------------------------------
__global__ __launch_bounds__(256)
void scores_mfma(const ushort* __restrict__ qk, const float* __restrict__ attb,
                 const float* __restrict__ alphat, float* __restrict__ att)
{
    __shared__ ushort Qs[64 * 128];
    __shared__ ushort Ks[64 * 128];
    const int np = blockIdx.x, s = blockIdx.y, tid = threadIdx.x;
    const int wave = tid >> 6, lane = tid & 63;
    const int quad = lane >> 4, l16 = lane & 15;
    const int tH = (wave >> 1) * 32, qH = (wave & 1) * 32;
    const ushort* qb = qk + ((size_t)np * 192 + s * 64) * PIX;
    const ushort* kb = qb + (size_t)32 * PIX;

    const int side = wave >> 1;
    const int cil = (wave & 1) * 2 + (lane >> 5);   // 0..3 within chunk
    const int t0 = (lane & 31) * 2;
    const ushort* sbase = (side ? kb : qb);
    ushort* dst = side ? Ks : Qs;

    f32x4 acc[2][2];
#pragma unroll
    for (int ms = 0; ms < 2; ++ms)
#pragma unroll
        for (int ns = 0; ns < 2; ++ns)
#pragma unroll
            for (int r = 0; r < 4; ++r) acc[ms][ns][r] = 0.f;

    for (int c = 0; c < 8; ++c) {
        __syncthreads();
        {
            const int ci = c * 4 + cil;
            const ushort* sb = sbase + (size_t)ci * PIX + t0;
            uint u[25];
#pragma unroll
            for (int v = 0; v < 25; ++v)
                u[v] = *(const uint*)(sb + v * 64);
            uint rA[16], rB[16];
#pragma unroll
            for (int w2 = 0; w2 < 12; ++w2) {
                uint a = u[2 * w2], b = u[2 * w2 + 1];
                rA[w2] = (a & 0xffffu) | (b << 16);
                rB[w2] = (a >> 16) | (b & 0xffff0000u);
            }
            rA[12] = u[24] & 0xffffu;  rB[12] = u[24] >> 16;
            rA[13] = 0u; rA[14] = 0u; rA[15] = 0u;
            rB[13] = 0u; rB[14] = 0u; rB[15] = 0u;
#pragma unroll
            for (int b4 = 0; b4 < 4; ++b4) {
                int blkA = (cil * 4 + b4) ^ (t0 & 7);
                int blkB = (cil * 4 + b4) ^ ((t0 + 1) & 7);
                uint4 wa, wb;
                wa.x = rA[b4 * 4 + 0]; wa.y = rA[b4 * 4 + 1];
                wa.z = rA[b4 * 4 + 2]; wa.w = rA[b4 * 4 + 3];
                wb.x = rB[b4 * 4 + 0]; wb.y = rB[b4 * 4 + 1];
                wb.z = rB[b4 * 4 + 2]; wb.w = rB[b4 * 4 + 3];
                *(uint4*)&dst[t0 * 128 + blkA * 8] = wa;
                *(uint4*)&dst[(t0 + 1) * 128 + blkB * 8] = wb;
            }
        }
        __syncthreads();
#pragma unroll
        for (int ks = 0; ks < 4; ++ks) {
            short8 a[2], b[2];
#pragma unroll
            for (int ms = 0; ms < 2; ++ms) {
                int t = tH + ms * 16 + l16;
                int blk = (ks * 4 + quad) ^ (t & 7);
                a[ms] = *(const short8*)&Qs[t * 128 + blk * 8];
            }
#pragma unroll
            for (int ns = 0; ns < 2; ++ns) {
                int q = qH + ns * 16 + l16;
                int blk = (ks * 4 + quad) ^ (q & 7);
                b[ns] = *(const short8*)&Ks[q * 128 + blk * 8];
            }
#pragma unroll
            for (int ms = 0; ms < 2; ++ms)
#pragma unroll
                for (int ns = 0; ns < 2; ++ns)
                    acc[ms][ns] = __builtin_amdgcn_mfma_f32_16x16x32_bf16(a[ms], b[ns], acc[ms][ns], 0, 0, 0);
        }
    }

    const float alpha = alphat[s];
    const int n = np / 6, p = np % 6;
    const float* bp2 = attb + (size_t)s * 4096;
    float* ap = att + ((size_t)(n * SS + s) * 6 + p) * 4096;
    const float inv = 1.0f / 800.0f;
#pragma unroll
    for (int ms = 0; ms < 2; ++ms)
#pragma unroll
        for (int ns = 0; ns < 2; ++ns) {
            int q = qH + ns * 16 + l16;
#pragma unroll
            for (int r = 0; r < 4; ++r) {
                int t = tH + ms * 16 + quad * 4 + r;
                ap[t * 64 + q] = bp2[t * 64 + q] + tanhf(acc[ms][ns][r] * inv) * alpha;
            }
        }
}

// ---------------------------------------------------------------------------
// Fused attention-apply + output conv, accumulating over s in registers.
//  Per block (np, v, zo): Z[np][zo*64+o][v*64+q] = b_out[..] +
//     sum_s sum_c W_out[o][s*128+c] * ( sum_t xr[np][c][v*64+t] * att_s[t][q] )
//  GEMM1: Y[c][q] = Xa[c][t] x Ta[q][t]   (m=c 128, n=q 64, k=t 64)
//  GEMM2: Z[o][q] += Wt[o][c] x Ys[q][c]  (m=o 64,  n=q 64, k=c 128)
//  Ys stored bf16 with 16B-block XOR swizzle (blk ^= q&7) for conflict-free
//  strided ds_read_b128.  LDS = 18432+9216+17408+16384 = 61440 B (2 blk/CU).
// ---------------------------------------------------------------------------
__global__ __launch_bounds__(256)
void attn_conv(const ushort* __restrict__ xr, const float* __restrict__ att,
               const ushort* __restrict__ Wo, const float* __restrict__ bias,
               float* __restrict__ Z)
{
    __shared__ ushort Xa[128 * 72];
    __shared__ ushort Ta[64 * 72];
    __shared__ ushort Wt[64 * 136];
    __shared__ ushort Ys[64 * 128];
    const int np = blockIdx.x, v = blockIdx.y, zo = blockIdx.z;
    const int tid = threadIdx.x;
    const int wave = tid >> 6, lane = tid & 63;
    const int quad = lane >> 4, l16 = lane & 15;
    const int mH = (wave & 1) * 64;    // GEMM1 c-split (64/wave-pair)
    const int oL = (wave & 1) * 32;    // GEMM2 o-split within the 64-chunk
    const int qH = (wave >> 1) * 32;   // q-split (32/wave-pair)
    const int n = np / 6, p = np % 6;

    // ---- stage Xa[c][t] once (coalesced from xr)
    {
        int cc = tid >> 1, half = tid & 1;
        const ushort* src = xr + ((size_t)np * 128 + cc) * PIX + v * 64 + half * 32;
        uint4 a = *(const uint4*)src;
        uint4 b = *(const uint4*)(src + 8);
        uint4 c0 = *(const uint4*)(src + 16);
        uint4 d = *(const uint4*)(src + 24);
        *(uint4*)&Xa[cc * 72 + half * 32] = a;
        *(uint4*)&Xa[cc * 72 + half * 32 + 8] = b;
        *(uint4*)&Xa[cc * 72 + half * 32 + 16] = c0;
        *(uint4*)&Xa[cc * 72 + half * 32 + 24] = d;
    }

    // ---- init Z accumulators with bias
    f32x4 acc2[2][2];
#pragma unroll
    for (int ms2 = 0; ms2 < 2; ++ms2) {
        float bv[4];
#pragma unroll
        for (int r = 0; r < 4; ++r)
            bv[r] = bias[zo * 64 + oL + ms2 * 16 + quad * 4 + r];
#pragma unroll
        for (int ns = 0; ns < 2; ++ns)
#pragma unroll
            for (int r = 0; r < 4; ++r) acc2[ms2][ns][r] = bv[r];
    }

    for (int s = 0; s < SS; ++s) {
        __syncthreads();   // prev GEMM1/GEMM2 reads done before restaging
        // ---- stage Ta[q][t] = att_s[t][q] (bf16, b32-packed)
        {
            int q = tid >> 2, seg = tid & 3;
            const float* ab = att + ((size_t)(n * SS + s) * 6 + p) * 4096;
#pragma unroll
            for (int i2 = 0; i2 < 8; ++i2) {
                int t0 = seg * 16 + i2 * 2;
                uint w = (uint)f2bf(ab[t0 * 64 + q]) | ((uint)f2bf(ab[(t0 + 1) * 64 + q]) << 16);
                *(uint*)&Ta[q * 72 + t0] = w;
            }
        }
        // ---- stage Wt[o][c] = Wo[(zo*64+o)*384 + s*128 + c]
        {
            int o = tid >> 2, seg = tid & 3;
            const ushort* wsrc = Wo + (size_t)(zo * 64 + o) * 384 + s * 128 + seg * 32;
            ushort* wd = &Wt[o * 136 + seg * 32];
            *(uint4*)wd = *(const uint4*)wsrc;
            *(uint4*)(wd + 8) = *(const uint4*)(wsrc + 8);
            *(uint4*)(wd + 16) = *(const uint4*)(wsrc + 16);
            *(uint4*)(wd + 24) = *(const uint4*)(wsrc + 24);
        }
        __syncthreads();
        // ---- GEMM1: Y = Xa x Ta
        f32x4 acc[4][2];
#pragma unroll
        for (int ms = 0; ms < 4; ++ms)
#pragma unroll
            for (int ns = 0; ns < 2; ++ns)
#pragma unroll
                for (int r = 0; r < 4; ++r) acc[ms][ns][r] = 0.f;
#pragma unroll
        for (int ks = 0; ks < 2; ++ks) {
            const int kk = ks * 32;
            short8 a[4], b[2];
#pragma unroll
            for (int ms = 0; ms < 4; ++ms)
                a[ms] = *(const short8*)&Xa[(mH + ms * 16 + l16) * 72 + kk + quad * 8];
#pragma unroll
            for (int ns = 0; ns < 2; ++ns)
                b[ns] = *(const short8*)&Ta[(qH + ns * 16 + l16) * 72 + kk + quad * 8];
#pragma unroll
            for (int ms = 0; ms < 4; ++ms)
#pragma unroll
                for (int ns = 0; ns < 2; ++ns)
                    acc[ms][ns] = __builtin_amdgcn_mfma_f32_16x16x32_bf16(a[ms], b[ns], acc[ms][ns], 0, 0, 0);
        }
        // ---- write Ys[q][c] bf16, swizzled (no barrier needed before: Ys
        //      reads of prev s were fenced by the loop-top barrier)
#pragma unroll
        for (int ms = 0; ms < 4; ++ms)
#pragma unroll
            for (int ns = 0; ns < 2; ++ns) {
                int q = qH + ns * 16 + l16;
                int c0 = mH + ms * 16 + quad * 4;
                uint w0 = (uint)f2bf(acc[ms][ns][0]) | ((uint)f2bf(acc[ms][ns][1]) << 16);
                uint w1 = (uint)f2bf(acc[ms][ns][2]) | ((uint)f2bf(acc[ms][ns][3]) << 16);
                int blk = (c0 >> 3) ^ (q & 7);
                ushort* d = &Ys[q * 128 + blk * 8 + (c0 & 7)];
                *(uint*)d = w0;
                *(uint*)(d + 2) = w1;
            }
        __syncthreads();
        // ---- GEMM2: Z += Wt x Ys
#pragma unroll
        for (int ks2 = 0; ks2 < 4; ++ks2) {
            short8 a2[2], b2[2];
#pragma unroll
            for (int ms2 = 0; ms2 < 2; ++ms2)
                a2[ms2] = *(const short8*)&Wt[(oL + ms2 * 16 + l16) * 136 + ks2 * 32 + quad * 8];
#pragma unroll
            for (int ns = 0; ns < 2; ++ns) {
                int q = qH + ns * 16 + l16;
                int blk = (ks2 * 4 + quad) ^ (q & 7);
                b2[ns] = *(const short8*)&Ys[q * 128 + blk * 8];
            }
#pragma unroll
            for (int ms2 = 0; ms2 < 2; ++ms2)
#pragma unroll
                for (int ns = 0; ns < 2; ++ns)
                    acc2[ms2][ns] = __builtin_amdgcn_mfma_f32_16x16x32_bf16(a2[ms2], b2[ns], acc2[ms2][ns], 0, 0, 0);
        }
    }

    // ---- epilogue: write Z fp32 in pix' order
    float* zp = Z + ((size_t)np * 128 + zo * 64) * PIX + v * 64;
#pragma unroll
    for (int ms2 = 0; ms2 < 2; ++ms2)
#pragma unroll
        for (int ns = 0; ns < 2; ++ns) {
            int q = qH + ns * 16 + l16;
#pragma unroll
            for (int r = 0; r < 4; ++r) {
                int o = oL + ms2 * 16 + quad * 4 + r;
                zp[(size_t)o * PIX + q] = acc2[ms2][ns][r];
            }
        }
}

// ---------------------------------------------------------------------------
// BN stats + finalize
// ---------------------------------------------------------------------------
__global__ void bn_stats(const float* __restrict__ z, float* __restrict__ stats) {
    const int c = blockIdx.x, np = blockIdx.y, tid = threadIdx.x;
    const float* zp = z + ((size_t)np * CCH + c) * PIX;
    float s = 0.f, s2 = 0.f;
    for (int i = tid; i < PIX; i += 256) {
        float v = zp[i];
        s += v; s2 += v * v;
    }
    for (int off = 32; off; off >>= 1) {
        s += __shfl_down(s, off);
        s2 += __shfl_down(s2, off);
    }
    __shared__ float ls[4], ls2[4];
    const int w = tid >> 6, lane = tid & 63;
    if (lane == 0) { ls[w] = s; ls2[w] = s2; }
    __syncthreads();
    if (tid == 0) {
        s = ls[0] + ls[1] + ls[2] + ls[3];
        s2 = ls2[0] + ls2[1] + ls2[2] + ls2[3];
        atomicAdd(&stats[c], s);
        atomicAdd(&stats[128 + c], s2);
    }
}

__global__ void bn_finalize(const float* __restrict__ stats, const float* __restrict__ g,
                            const float* __restrict__ be, float* __restrict__ scsh) {
    const int c = threadIdx.x;
    float mean = stats[c] * (1.0f / EPC);
    float var = stats[128 + c] * (1.0f / EPC) - mean * mean;
    float inv = rsqrtf(var + 1e-5f);
    float sc = g[c] * inv;
    scsh[c] = sc;
    scsh[128 + c] = be[c] - mean * sc;
}

// ---------------------------------------------------------------------------
// res1: y1[i(orig)] = leaky(x[i] + bn(Z'[perm(i)]))   (Z' in pix' order)
// ---------------------------------------------------------------------------
__global__ void res_bn_g(const float* __restrict__ x, const float* __restrict__ z,
                         const float* __restrict__ scsh, float* __restrict__ out) {
    size_t i = ((size_t)blockIdx.x * 256 + threadIdx.x) * 4;
    size_t row = i / PIX;
    int p = (int)(i % PIX);
    int ch = (int)(row & 127);
    float sc = scsh[ch], sh = scsh[128 + ch];
    const float* zr = z + row * PIX;
    float4 a = *(const float4*)(x + i);
    float xin[4] = {a.x, a.y, a.z, a.w};
    float4 r;
    float ro[4];
#pragma unroll
    for (int j = 0; j < 4; ++j) {
        int pp = p + j;
        int t = pp / 25, vv = pp - t * 25;
        float zz = zr[vv * 64 + t];
        float val = xin[j] + fmaf(zz, sc, sh);
        ro[j] = val >= 0.f ? val : 0.1f * val;
    }
    r.x = ro[0]; r.y = ro[1]; r.z = ro[2]; r.w = ro[3];
    *(float4*)(out + i) = r;
}

// ---------------------------------------------------------------------------
// res2: out = leaky(y1 + bn(z2)), all orig order, float4
// ---------------------------------------------------------------------------
__global__ void res_bn_l(const float4* __restrict__ xr, const float4* __restrict__ zr,
                         const float* __restrict__ scsh, float4* __restrict__ out) {
    int i = blockIdx.x * 256 + threadIdx.x;
    int row = i / 400;
    int ch = row & 127;
    float sc = scsh[ch], sh = scsh[128 + ch];
    float4 a = xr[i], b = zr[i], r;
    r.x = a.x + fmaf(b.x, sc, sh);
    r.y = a.y + fmaf(b.y, sc, sh);
    r.z = a.z + fmaf(b.z, sc, sh);
    r.w = a.w + fmaf(b.w, sc, sh);
    r.x = r.x >= 0.f ? r.x : 0.1f * r.x;
    r.y = r.y >= 0.f ? r.y : 0.1f * r.y;
    r.z = r.z >= 0.f ? r.z : 0.1f * r.z;
    r.w = r.w >= 0.f ? r.w : 0.1f * r.w;
    out[i] = r;
}

// ---------------------------------------------------------------------------
struct Ctx {
    ushort *xr, *Wp, *Wo, *Wf;
    float *bp;
    float *R1, *R0, *ATT, *STATS;
    const float *alphat, *b_out, *g_out, *be_out, *b_ff, *g_ff, *be_ff;
};

static void run_block(const float* X, const float* attb, float* OUT,
                      const Ctx& c, hipStream_t stream) {
    const int EG = 38400;   // 39,321,600 / (256*4)
    remap_x<<<EG, 256, 0, stream>>>(X, c.xr);
    // q/k conv -> QK (bf16, in R1), channels [q0|k0|q1|k1|q2|k2]
    gemm_conv<<<dim3(NPB, 13, 3), 256, 0, stream>>>(c.xr, 1, c.Wp, 128, c.bp,
                                                    (void*)c.R1, 1, 192, 0);
    scores_mfma<<<dim3(NPB, 3), 256, 0, stream>>>((const ushort*)c.R1, attb, c.alphat, c.ATT);
    // fused attention-apply + output conv (all 3 subsets), Z in R0 (fp32)
    attn_conv<<<dim3(NPB, VV, 2), 256, 0, stream>>>(c.xr, c.ATT, c.Wo, c.b_out, c.R0);
    hipMemsetAsync(c.STATS, 0, 256 * sizeof(float), stream);
    bn_stats<<<dim3(CCH, NPB), 256, 0, stream>>>(c.R0, c.STATS);
    bn_finalize<<<1, 128, 0, stream>>>(c.STATS, c.g_out, c.be_out, c.STATS + 256);
    res_bn_g<<<EG, 256, 0, stream>>>(X, c.R0, c.STATS + 256, c.R1);   // y1 fp32 in R1
    gemm_conv<<<dim3(NPB, 13, 2), 256, 0, stream>>>(c.R1, 0, c.Wf, 128, c.b_ff,
                                                    (void*)c.R0, 0, 128, 0);  // z2 in R0
    hipMemsetAsync(c.STATS, 0, 256 * sizeof(float), stream);
    bn_stats<<<dim3(CCH, NPB), 256, 0, stream>>>(c.R0, c.STATS);
    bn_finalize<<<1, 128, 0, stream>>>(c.STATS, c.g_ff, c.be_ff, c.STATS + 256);
    res_bn_l<<<EG, 256, 0, stream>>>((const float4*)c.R1, (const float4*)c.R0,
                                     c.STATS + 256, (float4*)OUT);
}

extern "C" void kernel_launch(void* const* d_in, const int* in_sizes, int n_in,
                              void* d_out, int out_size, void* d_ws, size_t ws_size,
                              hipStream_t stream) {
    const float* x = (const float*)d_in[0];
    const float* att1 = (const float*)d_in[1];
    const float* att2 = (const float*)d_in[2];
    Ctx c;
    c.alphat = (const float*)d_in[3];
    const float* w_in = (const float*)d_in[4];
    const float* b_in = (const float*)d_in[5];
    const float* w_out = (const float*)d_in[6];
    c.b_out = (const float*)d_in[7];
    c.g_out = (const float*)d_in[8];
    c.be_out = (const float*)d_in[9];
    const float* w_ff = (const float*)d_in[10];
    c.b_ff = (const float*)d_in[11];
    c.g_ff = (const float*)d_in[12];
    c.be_ff = (const float*)d_in[13];

    char* ws = (char*)d_ws;
    size_t off = 0;
    c.xr = (ushort*)(ws + off);   off += ETOT * 2;                    //  78.6 MB
    c.R1 = (float*)(ws + off);    off += ETOT * 4;                    // 157.3 MB
    c.R0 = (float*)(ws + off);    off += ETOT * 4;                    // 157.3 MB
    c.ATT = (float*)(ws + off);   off += (size_t)32 * 3 * 6 * 4096 * 4; // 9.4 MB
    c.STATS = (float*)(ws + off); off += 512 * 4;
    c.Wp = (ushort*)(ws + off);   off += 192 * 128 * 2;
    c.bp = (float*)(ws + off);    off += 192 * 4;
    c.Wo = (ushort*)(ws + off);   off += 128 * 384 * 2;
    c.Wf = (ushort*)(ws + off);   off += 128 * 128 * 2;

    wprep<<<192, 256, 0, stream>>>(w_in, b_in, w_out, w_ff, c.Wp, c.bp, c.Wo, c.Wf);

    float* out = (float*)d_out;
    run_block(x, att1, out, c, stream);
    run_block(out, att2, out, c, stream);
}

// Round 3
// 1583.304 us; speedup vs baseline: 1.4748x; 1.0506x over previous
//
#include <hip/hip_runtime.h>
#include <hip/hip_bf16.h>
#include <math.h>

// Problem constants
#define NPB  192            // N*P = 32*6
#define CCH  128
#define TT   64
#define VV   25
#define PIX  1600           // T*V
#define SS   3
#define EPC  307200.0f      // elems per channel for BN (192*1600)
static const size_t ETOT = (size_t)NPB * CCH * PIX;   // 39,321,600

typedef __attribute__((ext_vector_type(4))) float f32x4;
typedef __attribute__((ext_vector_type(8))) short short8;

__device__ __forceinline__ ushort f2bf(float f) {
    __hip_bfloat16 h = __float2bfloat16(f);
    return __builtin_bit_cast(unsigned short, h);
}
__device__ __forceinline__ float bf2f(ushort u) {
    unsigned int x = ((unsigned int)u) << 16;
    return __builtin_bit_cast(float, x);
}

// ---------------------------------------------------------------------------
// Weight prep: permute w_in rows to [q0|k0|q1|k1|q2|k2] (64-chunks), cvt bf16
// ---------------------------------------------------------------------------
__global__ void wprep(const float* __restrict__ w_in, const float* __restrict__ b_in,
                      const float* __restrict__ w_out, const float* __restrict__ w_ff,
                      ushort* __restrict__ Wp, float* __restrict__ bp,
                      ushort* __restrict__ Wo, ushort* __restrict__ Wf) {
    int i = blockIdx.x * 256 + threadIdx.x;   // grid covers 49152
    if (i < 192 * 128) {
        int r = i >> 7, c = i & 127;
        int s = r / 64, j = r % 64;
        int src = (j < 32) ? (s * 32 + j) : (96 + s * 32 + (j - 32));
        Wp[i] = f2bf(w_in[src * 128 + c]);
        if (c == 0) bp[r] = b_in[src];
    }
    if (i < 128 * 384) Wo[i] = f2bf(w_out[i]);
    if (i < 128 * 128) Wf[i] = f2bf(w_ff[i]);
}

// ---------------------------------------------------------------------------
// remap: xr[np][c][v*64+t] = bf16(x[np][c][t*25+v])
// ---------------------------------------------------------------------------
__global__ void remap_x(const float* __restrict__ x, ushort* __restrict__ xr) {
    size_t o = ((size_t)blockIdx.x * 256 + threadIdx.x) * 4;
    size_t row = o / PIX;
    int p = (int)(o % PIX);           // v*64 + t0, t0 multiple of 4
    int v = p >> 6, t0 = p & 63;
    const float* xp = x + row * PIX;
    uint2 u;
    u.x = (uint)f2bf(xp[(t0 + 0) * 25 + v]) | ((uint)f2bf(xp[(t0 + 1) * 25 + v]) << 16);
    u.y = (uint)f2bf(xp[(t0 + 2) * 25 + v]) | ((uint)f2bf(xp[(t0 + 3) * 25 + v]) << 16);
    *(uint2*)(xr + o) = u;
}

// ---------------------------------------------------------------------------
// MFMA conv GEMM: out[np][obase+o][pix] (+)= sum_{k<128} W[o][k]*in[np][k][pix]
// ---------------------------------------------------------------------------
__global__ __launch_bounds__(256)
void gemm_conv(const void* __restrict__ inp, int in_bf16,
               const ushort* __restrict__ W, int ldw,
               const float* __restrict__ bias,
               void* __restrict__ outp, int out_bf16, int out_ch,
               int accflag)
{
    __shared__ ushort Wt[64 * 72];
    __shared__ ushort Xt[128 * 72];
    const int np = blockIdx.x;
    const int pixbase = blockIdx.y * 128;
    const int obase = blockIdx.z * 64;
    const int tid = threadIdx.x;
    const int wave = tid >> 6, lane = tid & 63;
    const int quad = lane >> 4, l16 = lane & 15;
    const int wPix = wave * 32;

    f32x4 acc[4][2];
    if (accflag) {
        const float* op = (const float*)outp + ((size_t)np * out_ch + obase) * PIX + pixbase;
#pragma unroll
        for (int ms = 0; ms < 4; ++ms)
#pragma unroll
            for (int ns = 0; ns < 2; ++ns) {
                int pl = wPix + ns * 16 + l16;
                bool valid = (pixbase + pl) < PIX;
#pragma unroll
                for (int r = 0; r < 4; ++r) {
                    int ol = ms * 16 + quad * 4 + r;
                    acc[ms][ns][r] = valid ? op[(size_t)ol * PIX + pl] : 0.f;
                }
            }
    } else {
#pragma unroll
        for (int ms = 0; ms < 4; ++ms) {
            float bv[4];
#pragma unroll
            for (int r = 0; r < 4; ++r) {
                int ol = ms * 16 + quad * 4 + r;
                bv[r] = bias ? bias[obase + ol] : 0.f;
            }
#pragma unroll
            for (int ns = 0; ns < 2; ++ns)
#pragma unroll
                for (int r = 0; r < 4; ++r) acc[ms][ns][r] = bv[r];
        }
    }

    const ushort* inb = (const ushort*)inp;
    const float* inf = (const float*)inp;
    const size_t in_off = (size_t)np * 128 * PIX;

    for (int kc = 0; kc < 2; ++kc) {
        const int kbase = kc * 64;
        {
            int o = tid >> 2, seg = tid & 3;
            const ushort* src = W + (size_t)(obase + o) * ldw + kbase + seg * 16;
            uint4 a = *(const uint4*)src;
            uint4 b = *(const uint4*)(src + 8);
            *(uint4*)&Wt[o * 72 + seg * 16] = a;
            *(uint4*)&Wt[o * 72 + seg * 16 + 8] = b;
        }
        {
            int cp = tid & 31, rq = tid >> 5;
            int c = cp * 2;
            int p0 = rq * 16;
            bool valid = (pixbase + p0) < PIX;
            if (in_bf16) {
                uint ra[8], rb[8];
                if (valid) {
                    const ushort* s0 = inb + in_off + (size_t)(kbase + c) * PIX + pixbase + p0;
                    const ushort* s1 = s0 + PIX;
                    *(uint4*)&ra[0] = *(const uint4*)s0;
                    *(uint4*)&ra[4] = *(const uint4*)(s0 + 8);
                    *(uint4*)&rb[0] = *(const uint4*)s1;
                    *(uint4*)&rb[4] = *(const uint4*)(s1 + 8);
                } else {
#pragma unroll
                    for (int h = 0; h < 8; ++h) { ra[h] = 0; rb[h] = 0; }
                }
#pragma unroll
                for (int h = 0; h < 8; ++h) {
                    uint lo = ra[h], hi = rb[h];
                    *(uint*)&Xt[(p0 + 2 * h) * 72 + c] = (lo & 0xffffu) | (hi << 16);
                    *(uint*)&Xt[(p0 + 2 * h + 1) * 72 + c] = (lo >> 16) | (hi & 0xffff0000u);
                }
            } else {
                if (valid) {
                    const float* s0 = inf + in_off + (size_t)(kbase + c) * PIX + pixbase + p0;
                    const float* s1 = s0 + PIX;
#pragma unroll
                    for (int b4 = 0; b4 < 4; ++b4) {
                        float4 u = ((const float4*)s0)[b4];
                        float4 w4 = ((const float4*)s1)[b4];
                        int p = p0 + b4 * 4;
                        *(uint*)&Xt[(p + 0) * 72 + c] = (uint)f2bf(u.x) | ((uint)f2bf(w4.x) << 16);
                        *(uint*)&Xt[(p + 1) * 72 + c] = (uint)f2bf(u.y) | ((uint)f2bf(w4.y) << 16);
                        *(uint*)&Xt[(p + 2) * 72 + c] = (uint)f2bf(u.z) | ((uint)f2bf(w4.z) << 16);
                        *(uint*)&Xt[(p + 3) * 72 + c] = (uint)f2bf(u.w) | ((uint)f2bf(w4.w) << 16);
                    }
                } else {
#pragma unroll
                    for (int h = 0; h < 16; ++h) *(uint*)&Xt[(p0 + h) * 72 + c] = 0;
                }
            }
        }
        __syncthreads();
#pragma unroll
        for (int ks = 0; ks < 2; ++ks) {
            const int kk = ks * 32;
            short8 a[4], b[2];
#pragma unroll
            for (int ms = 0; ms < 4; ++ms)
                a[ms] = *(const short8*)&Wt[(ms * 16 + l16) * 72 + kk + quad * 8];
#pragma unroll
            for (int ns = 0; ns < 2; ++ns)
                b[ns] = *(const short8*)&Xt[(wPix + ns * 16 + l16) * 72 + kk + quad * 8];
#pragma unroll
            for (int ms = 0; ms < 4; ++ms)
#pragma unroll
                for (int ns = 0; ns < 2; ++ns)
                    acc[ms][ns] = __builtin_amdgcn_mfma_f32_16x16x32_bf16(a[ms], b[ns], acc[ms][ns], 0, 0, 0);
        }
        __syncthreads();
    }

    if (out_bf16) {
        ushort* op = (ushort*)outp + ((size_t)np * out_ch + obase) * PIX + pixbase;
#pragma unroll
        for (int ms = 0; ms < 4; ++ms)
#pragma unroll
            for (int ns = 0; ns < 2; ++ns) {
                int pl = wPix + ns * 16 + l16;
                if (pixbase + pl >= PIX) continue;
#pragma unroll
                for (int r = 0; r < 4; ++r) {
                    int ol = ms * 16 + quad * 4 + r;
                    op[(size_t)ol * PIX + pl] = f2bf(acc[ms][ns][r]);
                }
            }
    } else {
        float* op = (float*)outp + ((size_t)np * out_ch + obase) * PIX + pixbase;
#pragma unroll
        for (int ms = 0; ms < 4; ++ms)
#pragma unroll
            for (int ns = 0; ns < 2; ++ns) {
                int pl = wPix + ns * 16 + l16;
                if (pixbase + pl >= PIX) continue;
#pragma unroll
                for (int r = 0; r < 4; ++r) {
                    int ol = ms * 16 + quad * 4 + r;
                    op[(size_t)ol * PIX + pl] = acc[ms][ns][r];
                }
            }
    }
}

// ---------------------------------------------------------------------------
// scores via MFMA: att[n,s,p,t,q] = attb + tanh( (Q·K)/800 )*alpha
// ---------------------------------------------------------------------------
__global__ __launch_bounds__(256)
void scores_mfma(const ushort* __restrict__ qk, const float* __restrict__ attb,
                 const float* __restrict__ alphat, float* __restrict__ att)
{
    __shared__ ushort Qs[64 * 128];
    __shared__ ushort Ks[64 * 128];
    const int np = blockIdx.x, s = blockIdx.y, tid = threadIdx.x;
    const int wave = tid >> 6, lane = tid & 63;
    const int quad = lane >> 4, l16 = lane & 15;
    const int tH = (wave >> 1) * 32, qH = (wave & 1) * 32;
    const ushort* qb = qk + ((size_t)np * 192 + s * 64) * PIX;
    const ushort* kb = qb + (size_t)32 * PIX;

    const int side = wave >> 1;
    const int cil = (wave & 1) * 2 + (lane >> 5);   // 0..3 within chunk
    const int t0 = (lane & 31) * 2;
    const ushort* sbase = (side ? kb : qb);
    ushort* dst = side ? Ks : Qs;

    f32x4 acc[2][2];
#pragma unroll
    for (int ms = 0; ms < 2; ++ms)
#pragma unroll
        for (int ns = 0; ns < 2; ++ns)
#pragma unroll
            for (int r = 0; r < 4; ++r) acc[ms][ns][r] = 0.f;

    for (int c = 0; c < 8; ++c) {
        __syncthreads();
        {
            const int ci = c * 4 + cil;
            const ushort* sb = sbase + (size_t)ci * PIX + t0;
            uint u[25];
#pragma unroll
            for (int v = 0; v < 25; ++v)
                u[v] = *(const uint*)(sb + v * 64);
            uint rA[16], rB[16];
#pragma unroll
            for (int w2 = 0; w2 < 12; ++w2) {
                uint a = u[2 * w2], b = u[2 * w2 + 1];
                rA[w2] = (a & 0xffffu) | (b << 16);
                rB[w2] = (a >> 16) | (b & 0xffff0000u);
            }
            rA[12] = u[24] & 0xffffu;  rB[12] = u[24] >> 16;
            rA[13] = 0u; rA[14] = 0u; rA[15] = 0u;
            rB[13] = 0u; rB[14] = 0u; rB[15] = 0u;
#pragma unroll
            for (int b4 = 0; b4 < 4; ++b4) {
                int blkA = (cil * 4 + b4) ^ (t0 & 7);
                int blkB = (cil * 4 + b4) ^ ((t0 + 1) & 7);
                uint4 wa, wb;
                wa.x = rA[b4 * 4 + 0]; wa.y = rA[b4 * 4 + 1];
                wa.z = rA[b4 * 4 + 2]; wa.w = rA[b4 * 4 + 3];
                wb.x = rB[b4 * 4 + 0]; wb.y = rB[b4 * 4 + 1];
                wb.z = rB[b4 * 4 + 2]; wb.w = rB[b4 * 4 + 3];
                *(uint4*)&dst[t0 * 128 + blkA * 8] = wa;
                *(uint4*)&dst[(t0 + 1) * 128 + blkB * 8] = wb;
            }
        }
        __syncthreads();
#pragma unroll
        for (int ks = 0; ks < 4; ++ks) {
            short8 a[2], b[2];
#pragma unroll
            for (int ms = 0; ms < 2; ++ms) {
                int t = tH + ms * 16 + l16;
                int blk = (ks * 4 + quad) ^ (t & 7);
                a[ms] = *(const short8*)&Qs[t * 128 + blk * 8];
            }
#pragma unroll
            for (int ns = 0; ns < 2; ++ns) {
                int q = qH + ns * 16 + l16;
                int blk = (ks * 4 + quad) ^ (q & 7);
                b[ns] = *(const short8*)&Ks[q * 128 + blk * 8];
            }
#pragma unroll
            for (int ms = 0; ms < 2; ++ms)
#pragma unroll
                for (int ns = 0; ns < 2; ++ns)
                    acc[ms][ns] = __builtin_amdgcn_mfma_f32_16x16x32_bf16(a[ms], b[ns], acc[ms][ns], 0, 0, 0);
        }
    }

    const float alpha = alphat[s];
    const int n = np / 6, p = np % 6;
    const float* bp2 = attb + (size_t)s * 4096;
    float* ap = att + ((size_t)(n * SS + s) * 6 + p) * 4096;
    const float inv = 1.0f / 800.0f;
#pragma unroll
    for (int ms = 0; ms < 2; ++ms)
#pragma unroll
        for (int ns = 0; ns < 2; ++ns) {
            int q = qH + ns * 16 + l16;
#pragma unroll
            for (int r = 0; r < 4; ++r) {
                int t = tH + ms * 16 + quad * 4 + r;
                ap[t * 64 + q] = bp2[t * 64 + q] + tanhf(acc[ms][ns][r] * inv) * alpha;
            }
        }
}

// ---------------------------------------------------------------------------
// Fused attention-apply + output conv, accumulating over s in registers.
//  All LDS unpadded + 16B-block XOR swizzle (blk ^= row&7): conflict-free.
//  W fragments come straight from L2 into registers (no Wt tile).
//  LDS = 40960 B -> 4 blocks/CU.
// ---------------------------------------------------------------------------
__global__ __launch_bounds__(256, 4)
void attn_conv(const ushort* __restrict__ xr, const float* __restrict__ att,
               const ushort* __restrict__ Wo, const float* __restrict__ bias,
               float* __restrict__ Z)
{
    __shared__ ushort Xa[128 * 64];   // [c][t] swizzled
    __shared__ ushort Ta[64 * 64];    // [q][t] swizzled
    __shared__ ushort Ys[64 * 128];   // [q][c] swizzled
    const int np = blockIdx.x, v = blockIdx.y, zo = blockIdx.z;
    const int tid = threadIdx.x;
    const int wave = tid >> 6, lane = tid & 63;
    const int quad = lane >> 4, l16 = lane & 15;
    const int mH = (wave & 1) * 64;    // GEMM1 c-split
    const int oL = (wave & 1) * 32;    // GEMM2 o-split
    const int qH = (wave >> 1) * 32;   // q-split
    const int n = np / 6, p = np % 6;

    // ---- stage Xa[c][t] once (coalesced, swizzled b128 writes)
    {
        int cc = tid >> 1, half = tid & 1;
        const ushort* src = xr + ((size_t)np * 128 + cc) * PIX + v * 64 + half * 32;
        uint4 a = *(const uint4*)src;
        uint4 b = *(const uint4*)(src + 8);
        uint4 c0 = *(const uint4*)(src + 16);
        uint4 d = *(const uint4*)(src + 24);
        int sw = cc & 7;
        ushort* xb = &Xa[cc * 64];
        *(uint4*)&xb[((half * 4 + 0) ^ sw) * 8] = a;
        *(uint4*)&xb[((half * 4 + 1) ^ sw) * 8] = b;
        *(uint4*)&xb[((half * 4 + 2) ^ sw) * 8] = c0;
        *(uint4*)&xb[((half * 4 + 3) ^ sw) * 8] = d;
    }

    // ---- init Z accumulators with bias
    f32x4 acc2[2][2];
#pragma unroll
    for (int ms2 = 0; ms2 < 2; ++ms2) {
        float bv[4];
#pragma unroll
        for (int r = 0; r < 4; ++r)
            bv[r] = bias[zo * 64 + oL + ms2 * 16 + quad * 4 + r];
#pragma unroll
        for (int ns = 0; ns < 2; ++ns)
#pragma unroll
            for (int r = 0; r < 4; ++r) acc2[ms2][ns][r] = bv[r];
    }

    for (int s = 0; s < SS; ++s) {
        __syncthreads();   // prev GEMM1 Xa/Ta reads + prev GEMM2 Ys reads done
        // ---- stage Ta[q][t]: wave owns t-range wave*16..+15, lane = q
        {
            const float* ab = att + ((size_t)(n * SS + s) * 6 + p) * 4096
                              + (size_t)(wave * 16) * 64 + lane;
            ushort tv[16];
#pragma unroll
            for (int i = 0; i < 16; ++i)
                tv[i] = f2bf(ab[i * 64]);
            uint4 wlo, whi;
            wlo.x = (uint)tv[0] | ((uint)tv[1] << 16);
            wlo.y = (uint)tv[2] | ((uint)tv[3] << 16);
            wlo.z = (uint)tv[4] | ((uint)tv[5] << 16);
            wlo.w = (uint)tv[6] | ((uint)tv[7] << 16);
            whi.x = (uint)tv[8] | ((uint)tv[9] << 16);
            whi.y = (uint)tv[10] | ((uint)tv[11] << 16);
            whi.z = (uint)tv[12] | ((uint)tv[13] << 16);
            whi.w = (uint)tv[14] | ((uint)tv[15] << 16);
            int sw = lane & 7;
            ushort* tb = &Ta[lane * 64];
            *(uint4*)&tb[((wave * 2 + 0) ^ sw) * 8] = wlo;
            *(uint4*)&tb[((wave * 2 + 1) ^ sw) * 8] = whi;
        }
        __syncthreads();
        // ---- GEMM1: Y = Xa x Ta
        f32x4 acc[4][2];
#pragma unroll
        for (int ms = 0; ms < 4; ++ms)
#pragma unroll
            for (int ns = 0; ns < 2; ++ns)
#pragma unroll
                for (int r = 0; r < 4; ++r) acc[ms][ns][r] = 0.f;
#pragma unroll
        for (int ks = 0; ks < 2; ++ks) {
            short8 a[4], b[2];
#pragma unroll
            for (int ms = 0; ms < 4; ++ms) {
                int row = mH + ms * 16 + l16;
                int blk = (ks * 4 + quad) ^ (l16 & 7);
                a[ms] = *(const short8*)&Xa[row * 64 + blk * 8];
            }
#pragma unroll
            for (int ns = 0; ns < 2; ++ns) {
                int row = qH + ns * 16 + l16;
                int blk = (ks * 4 + quad) ^ (l16 & 7);
                b[ns] = *(const short8*)&Ta[row * 64 + blk * 8];
            }
#pragma unroll
            for (int ms = 0; ms < 4; ++ms)
#pragma unroll
                for (int ns = 0; ns < 2; ++ns)
                    acc[ms][ns] = __builtin_amdgcn_mfma_f32_16x16x32_bf16(a[ms], b[ns], acc[ms][ns], 0, 0, 0);
        }
        // ---- write Ys[q][c] bf16, swizzled
#pragma unroll
        for (int ms = 0; ms < 4; ++ms)
#pragma unroll
            for (int ns = 0; ns < 2; ++ns) {
                int q = qH + ns * 16 + l16;
                int c0 = mH + ms * 16 + quad * 4;
                uint w0 = (uint)f2bf(acc[ms][ns][0]) | ((uint)f2bf(acc[ms][ns][1]) << 16);
                uint w1 = (uint)f2bf(acc[ms][ns][2]) | ((uint)f2bf(acc[ms][ns][3]) << 16);
                int blk = (c0 >> 3) ^ (q & 7);
                ushort* d = &Ys[q * 128 + blk * 8 + (c0 & 7)];
                *(uint*)d = w0;
                *(uint*)(d + 2) = w1;
            }
        __syncthreads();
        // ---- load W fragments for this s straight from L2
        short8 wf[2][4];
        {
            const ushort* wb = Wo + (size_t)(zo * 64 + oL + l16) * 384 + s * 128 + quad * 8;
#pragma unroll
            for (int ms2 = 0; ms2 < 2; ++ms2)
#pragma unroll
                for (int ks2 = 0; ks2 < 4; ++ks2)
                    wf[ms2][ks2] = *(const short8*)(wb + ms2 * 16 * 384 + ks2 * 32);
        }
        // ---- GEMM2: Z += Wreg x Ys
#pragma unroll
        for (int ks2 = 0; ks2 < 4; ++ks2) {
            short8 b2[2];
#pragma unroll
            for (int ns = 0; ns < 2; ++ns) {
                int q = qH + ns * 16 + l16;
                int blk = (ks2 * 4 + quad) ^ (q & 7);
                b2[ns] = *(const short8*)&Ys[q * 128 + blk * 8];
            }
#pragma unroll
            for (int ms2 = 0; ms2 < 2; ++ms2)
#pragma unroll
                for (int ns = 0; ns < 2; ++ns)
                    acc2[ms2][ns] = __builtin_amdgcn_mfma_f32_16x16x32_bf16(wf[ms2][ks2], b2[ns], acc2[ms2][ns], 0, 0, 0);
        }
    }

    // ---- epilogue: write Z fp32 in pix' order
    float* zp = Z + ((size_t)np * 128 + zo * 64) * PIX + v * 64;
#pragma unroll
    for (int ms2 = 0; ms2 < 2; ++ms2)
#pragma unroll
        for (int ns = 0; ns < 2; ++ns) {
            int q = qH + ns * 16 + l16;
#pragma unroll
            for (int r = 0; r < 4; ++r) {
                int o = oL + ms2 * 16 + quad * 4 + r;
                zp[(size_t)o * PIX + q] = acc2[ms2][ns][r];
            }
        }
}

// ---------------------------------------------------------------------------
// BN stats + finalize
// ---------------------------------------------------------------------------
__global__ void bn_stats(const float* __restrict__ z, float* __restrict__ stats) {
    const int c = blockIdx.x, np = blockIdx.y, tid = threadIdx.x;
    const float* zp = z + ((size_t)np * CCH + c) * PIX;
    float s = 0.f, s2 = 0.f;
    for (int i = tid; i < PIX; i += 256) {
        float v = zp[i];
        s += v; s2 += v * v;
    }
    for (int off = 32; off; off >>= 1) {
        s += __shfl_down(s, off);
        s2 += __shfl_down(s2, off);
    }
    __shared__ float ls[4], ls2[4];
    const int w = tid >> 6, lane = tid & 63;
    if (lane == 0) { ls[w] = s; ls2[w] = s2; }
    __syncthreads();
    if (tid == 0) {
        s = ls[0] + ls[1] + ls[2] + ls[3];
        s2 = ls2[0] + ls2[1] + ls2[2] + ls2[3];
        atomicAdd(&stats[c], s);
        atomicAdd(&stats[128 + c], s2);
    }
}

__global__ void bn_finalize(const float* __restrict__ stats, const float* __restrict__ g,
                            const float* __restrict__ be, float* __restrict__ scsh) {
    const int c = threadIdx.x;
    float mean = stats[c] * (1.0f / EPC);
    float var = stats[128 + c] * (1.0f / EPC) - mean * mean;
    float inv = rsqrtf(var + 1e-5f);
    float sc = g[c] * inv;
    scsh[c] = sc;
    scsh[128 + c] = be[c] - mean * sc;
}

// ---------------------------------------------------------------------------
// res1: y1 = leaky(x + bn(Z')), fp32 out + bf16 copy (same rounding as before)
// ---------------------------------------------------------------------------
__global__ void res_bn_g(const float* __restrict__ x, const float* __restrict__ z,
                         const float* __restrict__ scsh, float* __restrict__ out,
                         ushort* __restrict__ outb) {
    size_t i = ((size_t)blockIdx.x * 256 + threadIdx.x) * 4;
    size_t row = i / PIX;
    int p = (int)(i % PIX);
    int ch = (int)(row & 127);
    float sc = scsh[ch], sh = scsh[128 + ch];
    const float* zr = z + row * PIX;
    float4 a = *(const float4*)(x + i);
    float xin[4] = {a.x, a.y, a.z, a.w};
    float4 r;
    float ro[4];
#pragma unroll
    for (int j = 0; j < 4; ++j) {
        int pp = p + j;
        int t = pp / 25, vv = pp - t * 25;
        float zz = zr[vv * 64 + t];
        float val = xin[j] + fmaf(zz, sc, sh);
        ro[j] = val >= 0.f ? val : 0.1f * val;
    }
    r.x = ro[0]; r.y = ro[1]; r.z = ro[2]; r.w = ro[3];
    *(float4*)(out + i) = r;
    uint2 ub;
    ub.x = (uint)f2bf(ro[0]) | ((uint)f2bf(ro[1]) << 16);
    ub.y = (uint)f2bf(ro[2]) | ((uint)f2bf(ro[3]) << 16);
    *(uint2*)(outb + i) = ub;
}

// ---------------------------------------------------------------------------
// res2: out = leaky(y1 + bn(z2)), all orig order, float4
// ---------------------------------------------------------------------------
__global__ void res_bn_l(const float4* __restrict__ xr, const float4* __restrict__ zr,
                         const float* __restrict__ scsh, float4* __restrict__ out) {
    int i = blockIdx.x * 256 + threadIdx.x;
    int row = i / 400;
    int ch = row & 127;
    float sc = scsh[ch], sh = scsh[128 + ch];
    float4 a = xr[i], b = zr[i], r;
    r.x = a.x + fmaf(b.x, sc, sh);
    r.y = a.y + fmaf(b.y, sc, sh);
    r.z = a.z + fmaf(b.z, sc, sh);
    r.w = a.w + fmaf(b.w, sc, sh);
    r.x = r.x >= 0.f ? r.x : 0.1f * r.x;
    r.y = r.y >= 0.f ? r.y : 0.1f * r.y;
    r.z = r.z >= 0.f ? r.z : 0.1f * r.z;
    r.w = r.w >= 0.f ? r.w : 0.1f * r.w;
    out[i] = r;
}

// ---------------------------------------------------------------------------
struct Ctx {
    ushort *xr, *Wp, *Wo, *Wf;
    float *bp;
    float *R1, *R0, *ATT, *STATS;
    const float *alphat, *b_out, *g_out, *be_out, *b_ff, *g_ff, *be_ff;
};

static void run_block(const float* X, const float* attb, float* OUT,
                      const Ctx& c, hipStream_t stream) {
    const int EG = 38400;   // 39,321,600 / (256*4)
    remap_x<<<EG, 256, 0, stream>>>(X, c.xr);
    // q/k conv -> QK (bf16, in R1), channels [q0|k0|q1|k1|q2|k2]
    gemm_conv<<<dim3(NPB, 13, 3), 256, 0, stream>>>(c.xr, 1, c.Wp, 128, c.bp,
                                                    (void*)c.R1, 1, 192, 0);
    scores_mfma<<<dim3(NPB, 3), 256, 0, stream>>>((const ushort*)c.R1, attb, c.alphat, c.ATT);
    // fused attention-apply + output conv (all 3 subsets), Z in R0 (fp32)
    attn_conv<<<dim3(NPB, VV, 2), 256, 0, stream>>>(c.xr, c.ATT, c.Wo, c.b_out, c.R0);
    hipMemsetAsync(c.STATS, 0, 256 * sizeof(float), stream);
    bn_stats<<<dim3(CCH, NPB), 256, 0, stream>>>(c.R0, c.STATS);
    bn_finalize<<<1, 128, 0, stream>>>(c.STATS, c.g_out, c.be_out, c.STATS + 256);
    // y1 fp32 in R1, y1 bf16 in xr (xr is dead for the rest of this block)
    res_bn_g<<<EG, 256, 0, stream>>>(X, c.R0, c.STATS + 256, c.R1, c.xr);
    gemm_conv<<<dim3(NPB, 13, 2), 256, 0, stream>>>(c.xr, 1, c.Wf, 128, c.b_ff,
                                                    (void*)c.R0, 0, 128, 0);  // z2 in R0
    hipMemsetAsync(c.STATS, 0, 256 * sizeof(float), stream);
    bn_stats<<<dim3(CCH, NPB), 256, 0, stream>>>(c.R0, c.STATS);
    bn_finalize<<<1, 128, 0, stream>>>(c.STATS, c.g_ff, c.be_ff, c.STATS + 256);
    res_bn_l<<<EG, 256, 0, stream>>>((const float4*)c.R1, (const float4*)c.R0,
                                     c.STATS + 256, (float4*)OUT);
}

extern "C" void kernel_launch(void* const* d_in, const int* in_sizes, int n_in,
                              void* d_out, int out_size, void* d_ws, size_t ws_size,
                              hipStream_t stream) {
    const float* x = (const float*)d_in[0];
    const float* att1 = (const float*)d_in[1];
    const float* att2 = (const float*)d_in[2];
    Ctx c;
    c.alphat = (const float*)d_in[3];
    const float* w_in = (const float*)d_in[4];
    const float* b_in = (const float*)d_in[5];
    const float* w_out = (const float*)d_in[6];
    c.b_out = (const float*)d_in[7];
    c.g_out = (const float*)d_in[8];
    c.be_out = (const float*)d_in[9];
    const float* w_ff = (const float*)d_in[10];
    c.b_ff = (const float*)d_in[11];
    c.g_ff = (const float*)d_in[12];
    c.be_ff = (const float*)d_in[13];

    char* ws = (char*)d_ws;
    size_t off = 0;
    c.xr = (ushort*)(ws + off);   off += ETOT * 2;                    //  78.6 MB
    c.R1 = (float*)(ws + off);    off += ETOT * 4;                    // 157.3 MB
    c.R0 = (float*)(ws + off);    off += ETOT * 4;                    // 157.3 MB
    c.ATT = (float*)(ws + off);   off += (size_t)32 * 3 * 6 * 4096 * 4; // 9.4 MB
    c.STATS = (float*)(ws + off); off += 512 * 4;
    c.Wp = (ushort*)(ws + off);   off += 192 * 128 * 2;
    c.bp = (float*)(ws + off);    off += 192 * 4;
    c.Wo = (ushort*)(ws + off);   off += 128 * 384 * 2;
    c.Wf = (ushort*)(ws + off);   off += 128 * 128 * 2;

    wprep<<<192, 256, 0, stream>>>(w_in, b_in, w_out, w_ff, c.Wp, c.bp, c.Wo, c.Wf);

    float* out = (float*)d_out;
    run_block(x, att1, out, c, stream);
    run_block(out, att2, out, c, stream);
}

// Round 4
// 1570.073 us; speedup vs baseline: 1.4873x; 1.0084x over previous
//
#include <hip/hip_runtime.h>
#include <hip/hip_bf16.h>
#include <math.h>

// Problem constants
#define NPB  192            // N*P = 32*6
#define CCH  128
#define TT   64
#define VV   25
#define PIX  1600           // T*V
#define SS   3
#define EPC  307200.0f      // elems per channel for BN (192*1600)
static const size_t ETOT = (size_t)NPB * CCH * PIX;   // 39,321,600

typedef __attribute__((ext_vector_type(4))) float f32x4;
typedef __attribute__((ext_vector_type(8))) short short8;

__device__ __forceinline__ ushort f2bf(float f) {
    __hip_bfloat16 h = __float2bfloat16(f);
    return __builtin_bit_cast(unsigned short, h);
}
__device__ __forceinline__ float bf2f(ushort u) {
    unsigned int x = ((unsigned int)u) << 16;
    return __builtin_bit_cast(float, x);
}

// ---------------------------------------------------------------------------
// Weight prep: permute w_in rows to [q0|k0|q1|k1|q2|k2] (64-chunks), cvt bf16
// ---------------------------------------------------------------------------
__global__ void wprep(const float* __restrict__ w_in, const float* __restrict__ b_in,
                      const float* __restrict__ w_out, const float* __restrict__ w_ff,
                      ushort* __restrict__ Wp, float* __restrict__ bp,
                      ushort* __restrict__ Wo, ushort* __restrict__ Wf) {
    int i = blockIdx.x * 256 + threadIdx.x;   // grid covers 49152
    if (i < 192 * 128) {
        int r = i >> 7, c = i & 127;
        int s = r / 64, j = r % 64;
        int src = (j < 32) ? (s * 32 + j) : (96 + s * 32 + (j - 32));
        Wp[i] = f2bf(w_in[src * 128 + c]);
        if (c == 0) bp[r] = b_in[src];
    }
    if (i < 128 * 384) Wo[i] = f2bf(w_out[i]);
    if (i < 128 * 128) Wf[i] = f2bf(w_ff[i]);
}

// ---------------------------------------------------------------------------
// remap: xr[np][c][v*64+t] = bf16(x[np][c][t*25+v])
// ---------------------------------------------------------------------------
__global__ void remap_x(const float* __restrict__ x, ushort* __restrict__ xr) {
    size_t o = ((size_t)blockIdx.x * 256 + threadIdx.x) * 4;
    size_t row = o / PIX;
    int p = (int)(o % PIX);           // v*64 + t0, t0 multiple of 4
    int v = p >> 6, t0 = p & 63;
    const float* xp = x + row * PIX;
    uint2 u;
    u.x = (uint)f2bf(xp[(t0 + 0) * 25 + v]) | ((uint)f2bf(xp[(t0 + 1) * 25 + v]) << 16);
    u.y = (uint)f2bf(xp[(t0 + 2) * 25 + v]) | ((uint)f2bf(xp[(t0 + 3) * 25 + v]) << 16);
    *(uint2*)(xr + o) = u;
}

// ---------------------------------------------------------------------------
// MFMA conv GEMM: out[np][obase+o][pix] (+)= sum_{k<128} W[o][k]*in[np][k][pix]
// ---------------------------------------------------------------------------
__global__ __launch_bounds__(256)
void gemm_conv(const void* __restrict__ inp, int in_bf16,
               const ushort* __restrict__ W, int ldw,
               const float* __restrict__ bias,
               void* __restrict__ outp, int out_bf16, int out_ch,
               int accflag)
{
    __shared__ ushort Wt[64 * 72];
    __shared__ ushort Xt[128 * 72];
    const int np = blockIdx.x;
    const int pixbase = blockIdx.y * 128;
    const int obase = blockIdx.z * 64;
    const int tid = threadIdx.x;
    const int wave = tid >> 6, lane = tid & 63;
    const int quad = lane >> 4, l16 = lane & 15;
    const int wPix = wave * 32;

    f32x4 acc[4][2];
    if (accflag) {
        const float* op = (const float*)outp + ((size_t)np * out_ch + obase) * PIX + pixbase;
#pragma unroll
        for (int ms = 0; ms < 4; ++ms)
#pragma unroll
            for (int ns = 0; ns < 2; ++ns) {
                int pl = wPix + ns * 16 + l16;
                bool valid = (pixbase + pl) < PIX;
#pragma unroll
                for (int r = 0; r < 4; ++r) {
                    int ol = ms * 16 + quad * 4 + r;
                    acc[ms][ns][r] = valid ? op[(size_t)ol * PIX + pl] : 0.f;
                }
            }
    } else {
#pragma unroll
        for (int ms = 0; ms < 4; ++ms) {
            float bv[4];
#pragma unroll
            for (int r = 0; r < 4; ++r) {
                int ol = ms * 16 + quad * 4 + r;
                bv[r] = bias ? bias[obase + ol] : 0.f;
            }
#pragma unroll
            for (int ns = 0; ns < 2; ++ns)
#pragma unroll
                for (int r = 0; r < 4; ++r) acc[ms][ns][r] = bv[r];
        }
    }

    const ushort* inb = (const ushort*)inp;
    const float* inf = (const float*)inp;
    const size_t in_off = (size_t)np * 128 * PIX;

    for (int kc = 0; kc < 2; ++kc) {
        const int kbase = kc * 64;
        {
            int o = tid >> 2, seg = tid & 3;
            const ushort* src = W + (size_t)(obase + o) * ldw + kbase + seg * 16;
            uint4 a = *(const uint4*)src;
            uint4 b = *(const uint4*)(src + 8);
            *(uint4*)&Wt[o * 72 + seg * 16] = a;
            *(uint4*)&Wt[o * 72 + seg * 16 + 8] = b;
        }
        {
            int cp = tid & 31, rq = tid >> 5;
            int c = cp * 2;
            int p0 = rq * 16;
            bool valid = (pixbase + p0) < PIX;
            if (in_bf16) {
                uint ra[8], rb[8];
                if (valid) {
                    const ushort* s0 = inb + in_off + (size_t)(kbase + c) * PIX + pixbase + p0;
                    const ushort* s1 = s0 + PIX;
                    *(uint4*)&ra[0] = *(const uint4*)s0;
                    *(uint4*)&ra[4] = *(const uint4*)(s0 + 8);
                    *(uint4*)&rb[0] = *(const uint4*)s1;
                    *(uint4*)&rb[4] = *(const uint4*)(s1 + 8);
                } else {
#pragma unroll
                    for (int h = 0; h < 8; ++h) { ra[h] = 0; rb[h] = 0; }
                }
#pragma unroll
                for (int h = 0; h < 8; ++h) {
                    uint lo = ra[h], hi = rb[h];
                    *(uint*)&Xt[(p0 + 2 * h) * 72 + c] = (lo & 0xffffu) | (hi << 16);
                    *(uint*)&Xt[(p0 + 2 * h + 1) * 72 + c] = (lo >> 16) | (hi & 0xffff0000u);
                }
            } else {
                if (valid) {
                    const float* s0 = inf + in_off + (size_t)(kbase + c) * PIX + pixbase + p0;
                    const float* s1 = s0 + PIX;
#pragma unroll
                    for (int b4 = 0; b4 < 4; ++b4) {
                        float4 u = ((const float4*)s0)[b4];
                        float4 w4 = ((const float4*)s1)[b4];
                        int p = p0 + b4 * 4;
                        *(uint*)&Xt[(p + 0) * 72 + c] = (uint)f2bf(u.x) | ((uint)f2bf(w4.x) << 16);
                        *(uint*)&Xt[(p + 1) * 72 + c] = (uint)f2bf(u.y) | ((uint)f2bf(w4.y) << 16);
                        *(uint*)&Xt[(p + 2) * 72 + c] = (uint)f2bf(u.z) | ((uint)f2bf(w4.z) << 16);
                        *(uint*)&Xt[(p + 3) * 72 + c] = (uint)f2bf(u.w) | ((uint)f2bf(w4.w) << 16);
                    }
                } else {
#pragma unroll
                    for (int h = 0; h < 16; ++h) *(uint*)&Xt[(p0 + h) * 72 + c] = 0;
                }
            }
        }
        __syncthreads();
#pragma unroll
        for (int ks = 0; ks < 2; ++ks) {
            const int kk = ks * 32;
            short8 a[4], b[2];
#pragma unroll
            for (int ms = 0; ms < 4; ++ms)
                a[ms] = *(const short8*)&Wt[(ms * 16 + l16) * 72 + kk + quad * 8];
#pragma unroll
            for (int ns = 0; ns < 2; ++ns)
                b[ns] = *(const short8*)&Xt[(wPix + ns * 16 + l16) * 72 + kk + quad * 8];
#pragma unroll
            for (int ms = 0; ms < 4; ++ms)
#pragma unroll
                for (int ns = 0; ns < 2; ++ns)
                    acc[ms][ns] = __builtin_amdgcn_mfma_f32_16x16x32_bf16(a[ms], b[ns], acc[ms][ns], 0, 0, 0);
        }
        __syncthreads();
    }

    if (out_bf16) {
        ushort* op = (ushort*)outp + ((size_t)np * out_ch + obase) * PIX + pixbase;
#pragma unroll
        for (int ms = 0; ms < 4; ++ms)
#pragma unroll
            for (int ns = 0; ns < 2; ++ns) {
                int pl = wPix + ns * 16 + l16;
                if (pixbase + pl >= PIX) continue;
#pragma unroll
                for (int r = 0; r < 4; ++r) {
                    int ol = ms * 16 + quad * 4 + r;
                    op[(size_t)ol * PIX + pl] = f2bf(acc[ms][ns][r]);
                }
            }
    } else {
        float* op = (float*)outp + ((size_t)np * out_ch + obase) * PIX + pixbase;
#pragma unroll
        for (int ms = 0; ms < 4; ++ms)
#pragma unroll
            for (int ns = 0; ns < 2; ++ns) {
                int pl = wPix + ns * 16 + l16;
                if (pixbase + pl >= PIX) continue;
#pragma unroll
                for (int r = 0; r < 4; ++r) {
                    int ol = ms * 16 + quad * 4 + r;
                    op[(size_t)ol * PIX + pl] = acc[ms][ns][r];
                }
            }
    }
}

// ---------------------------------------------------------------------------
// scores via MFMA, TRANSPOSED output: attb_bf[n,s,p][q*64+t] =
//   bf16( attb[t][q] + tanh((Q·K)/800)*alpha )
//  Operands swapped vs R1 version: A = K (rows=q), B = Q (cols=t), so the
//  accumulator is [q][t] and the bf16 store is exactly the layout attn_conv
//  stages (f2bf at the same point as before -> identical numerics).
// ---------------------------------------------------------------------------
__global__ __launch_bounds__(256)
void scores_mfma(const ushort* __restrict__ qk, const float* __restrict__ attb,
                 const float* __restrict__ alphat, ushort* __restrict__ attq)
{
    __shared__ ushort Qs[64 * 128];
    __shared__ ushort Ks[64 * 128];
    const int np = blockIdx.x, s = blockIdx.y, tid = threadIdx.x;
    const int wave = tid >> 6, lane = tid & 63;
    const int quad = lane >> 4, l16 = lane & 15;
    const int qW = (wave >> 1) * 32, tW = (wave & 1) * 32;
    const ushort* qb = qk + ((size_t)np * 192 + s * 64) * PIX;
    const ushort* kb = qb + (size_t)32 * PIX;

    const int side = wave >> 1;
    const int cil = (wave & 1) * 2 + (lane >> 5);   // 0..3 within chunk
    const int t0 = (lane & 31) * 2;
    const ushort* sbase = (side ? kb : qb);
    ushort* dst = side ? Ks : Qs;

    f32x4 acc[2][2];
#pragma unroll
    for (int ms = 0; ms < 2; ++ms)
#pragma unroll
        for (int ns = 0; ns < 2; ++ns)
#pragma unroll
            for (int r = 0; r < 4; ++r) acc[ms][ns][r] = 0.f;

    for (int c = 0; c < 8; ++c) {
        __syncthreads();
        {
            const int ci = c * 4 + cil;
            const ushort* sb = sbase + (size_t)ci * PIX + t0;
            uint u[25];
#pragma unroll
            for (int v = 0; v < 25; ++v)
                u[v] = *(const uint*)(sb + v * 64);
            uint rA[16], rB[16];
#pragma unroll
            for (int w2 = 0; w2 < 12; ++w2) {
                uint a = u[2 * w2], b = u[2 * w2 + 1];
                rA[w2] = (a & 0xffffu) | (b << 16);
                rB[w2] = (a >> 16) | (b & 0xffff0000u);
            }
            rA[12] = u[24] & 0xffffu;  rB[12] = u[24] >> 16;
            rA[13] = 0u; rA[14] = 0u; rA[15] = 0u;
            rB[13] = 0u; rB[14] = 0u; rB[15] = 0u;
#pragma unroll
            for (int b4 = 0; b4 < 4; ++b4) {
                int blkA = (cil * 4 + b4) ^ (t0 & 7);
                int blkB = (cil * 4 + b4) ^ ((t0 + 1) & 7);
                uint4 wa, wb;
                wa.x = rA[b4 * 4 + 0]; wa.y = rA[b4 * 4 + 1];
                wa.z = rA[b4 * 4 + 2]; wa.w = rA[b4 * 4 + 3];
                wb.x = rB[b4 * 4 + 0]; wb.y = rB[b4 * 4 + 1];
                wb.z = rB[b4 * 4 + 2]; wb.w = rB[b4 * 4 + 3];
                *(uint4*)&dst[t0 * 128 + blkA * 8] = wa;
                *(uint4*)&dst[(t0 + 1) * 128 + blkB * 8] = wb;
            }
        }
        __syncthreads();
#pragma unroll
        for (int ks = 0; ks < 4; ++ks) {
            short8 a[2], b[2];
#pragma unroll
            for (int ms = 0; ms < 2; ++ms) {
                int q = qW + ms * 16 + l16;
                int blk = (ks * 4 + quad) ^ (q & 7);
                a[ms] = *(const short8*)&Ks[q * 128 + blk * 8];
            }
#pragma unroll
            for (int ns = 0; ns < 2; ++ns) {
                int t = tW + ns * 16 + l16;
                int blk = (ks * 4 + quad) ^ (t & 7);
                b[ns] = *(const short8*)&Qs[t * 128 + blk * 8];
            }
#pragma unroll
            for (int ms = 0; ms < 2; ++ms)
#pragma unroll
                for (int ns = 0; ns < 2; ++ns)
                    acc[ms][ns] = __builtin_amdgcn_mfma_f32_16x16x32_bf16(a[ms], b[ns], acc[ms][ns], 0, 0, 0);
        }
    }

    const float alpha = alphat[s];
    const int n = np / 6, p = np % 6;
    const float* bp2 = attb + (size_t)s * 4096;
    ushort* ap = attq + ((size_t)(n * SS + s) * 6 + p) * 4096;
    const float inv = 1.0f / 800.0f;
#pragma unroll
    for (int ms = 0; ms < 2; ++ms)
#pragma unroll
        for (int ns = 0; ns < 2; ++ns) {
            int t = tW + ns * 16 + l16;
#pragma unroll
            for (int r = 0; r < 4; ++r) {
                int q = qW + ms * 16 + quad * 4 + r;
                ap[q * 64 + t] = f2bf(bp2[t * 64 + q] + tanhf(acc[ms][ns][r] * inv) * alpha);
            }
        }
}

// ---------------------------------------------------------------------------
// Fused attention-apply + output conv, merged over zo (full 128 out-chans).
//  Per block (np, v): Z[np][o][v*64+q] = b_out[o] +
//     sum_s sum_c W_out[o][s*128+c] * ( sum_t xr[np][c][v*64+t] * att_s[t][q] )
//  GEMM1 once per s (no duplicate), Ta staged coalesced from pre-transposed
//  bf16 attq. W fragments streamed from L2 per ks2 (16 transient VGPR).
//  LDS 40960 B -> 4 blocks/CU; all tiles XOR-swizzled (blk ^= row&7).
// ---------------------------------------------------------------------------
__global__ __launch_bounds__(256, 4)
void attn_conv(const ushort* __restrict__ xr, const ushort* __restrict__ attq,
               const ushort* __restrict__ Wo, const float* __restrict__ bias,
               float* __restrict__ Z)
{
    __shared__ ushort Xa[128 * 64];   // [c][t] swizzled
    __shared__ ushort Ta[64 * 64];    // [q][t] swizzled
    __shared__ ushort Ys[64 * 128];   // [q][c] swizzled
    const int np = blockIdx.x, v = blockIdx.y;
    const int tid = threadIdx.x;
    const int wave = tid >> 6, lane = tid & 63;
    const int quad = lane >> 4, l16 = lane & 15;
    const int mH = (wave & 1) * 64;    // GEMM1 c-half
    const int oH = (wave & 1) * 64;    // GEMM2 o-half
    const int qH = (wave >> 1) * 32;   // q-half (both GEMMs)
    const int n = np / 6, p = np % 6;

    // ---- stage Xa[c][t] once (coalesced, swizzled b128 writes)
    {
        int cc = tid >> 1, half = tid & 1;
        const ushort* src = xr + ((size_t)np * 128 + cc) * PIX + v * 64 + half * 32;
        uint4 a = *(const uint4*)src;
        uint4 b = *(const uint4*)(src + 8);
        uint4 c0 = *(const uint4*)(src + 16);
        uint4 d = *(const uint4*)(src + 24);
        int sw = cc & 7;
        ushort* xb = &Xa[cc * 64];
        *(uint4*)&xb[((half * 4 + 0) ^ sw) * 8] = a;
        *(uint4*)&xb[((half * 4 + 1) ^ sw) * 8] = b;
        *(uint4*)&xb[((half * 4 + 2) ^ sw) * 8] = c0;
        *(uint4*)&xb[((half * 4 + 3) ^ sw) * 8] = d;
    }

    // ---- init Z accumulators with bias (o = oH + ms2*16 + quad*4 + r)
    f32x4 acc2[4][2];
#pragma unroll
    for (int ms2 = 0; ms2 < 4; ++ms2) {
        float bv[4];
#pragma unroll
        for (int r = 0; r < 4; ++r)
            bv[r] = bias[oH + ms2 * 16 + quad * 4 + r];
#pragma unroll
        for (int ns = 0; ns < 2; ++ns)
#pragma unroll
            for (int r = 0; r < 4; ++r) acc2[ms2][ns][r] = bv[r];
    }

    const size_t abase = ((size_t)(n * SS) * 6 + p) * 4096;

    for (int s = 0; s < SS; ++s) {
        __syncthreads();   // prev GEMM1 Xa/Ta reads + prev GEMM2 Ys reads done
        // ---- stage Ta[q][t] from attq (coalesced 8KB, swizzled b128 writes)
        {
            int r0 = tid >> 2, seg = tid & 3;
            const ushort* src = attq + abase + (size_t)s * 6 * 4096 + r0 * 64 + seg * 16;
            uint4 a = *(const uint4*)src;
            uint4 b = *(const uint4*)(src + 8);
            int sw = r0 & 7;
            ushort* tb = &Ta[r0 * 64];
            *(uint4*)&tb[((seg * 2 + 0) ^ sw) * 8] = a;
            *(uint4*)&tb[((seg * 2 + 1) ^ sw) * 8] = b;
        }
        __syncthreads();
        // ---- GEMM1: Y = Xa x Ta  (m=c 128 split by mH, n=q 64 split by qH)
        f32x4 acc[4][2];
#pragma unroll
        for (int ms = 0; ms < 4; ++ms)
#pragma unroll
            for (int ns = 0; ns < 2; ++ns)
#pragma unroll
                for (int r = 0; r < 4; ++r) acc[ms][ns][r] = 0.f;
#pragma unroll
        for (int ks = 0; ks < 2; ++ks) {
            short8 a[4], b[2];
#pragma unroll
            for (int ms = 0; ms < 4; ++ms) {
                int row = mH + ms * 16 + l16;
                int blk = (ks * 4 + quad) ^ (l16 & 7);
                a[ms] = *(const short8*)&Xa[row * 64 + blk * 8];
            }
#pragma unroll
            for (int ns = 0; ns < 2; ++ns) {
                int row = qH + ns * 16 + l16;
                int blk = (ks * 4 + quad) ^ (l16 & 7);
                b[ns] = *(const short8*)&Ta[row * 64 + blk * 8];
            }
#pragma unroll
            for (int ms = 0; ms < 4; ++ms)
#pragma unroll
                for (int ns = 0; ns < 2; ++ns)
                    acc[ms][ns] = __builtin_amdgcn_mfma_f32_16x16x32_bf16(a[ms], b[ns], acc[ms][ns], 0, 0, 0);
        }
        // ---- write Ys[q][c] bf16, swizzled
#pragma unroll
        for (int ms = 0; ms < 4; ++ms)
#pragma unroll
            for (int ns = 0; ns < 2; ++ns) {
                int q = qH + ns * 16 + l16;
                int c0 = mH + ms * 16 + quad * 4;
                uint w0 = (uint)f2bf(acc[ms][ns][0]) | ((uint)f2bf(acc[ms][ns][1]) << 16);
                uint w1 = (uint)f2bf(acc[ms][ns][2]) | ((uint)f2bf(acc[ms][ns][3]) << 16);
                int blk = (c0 >> 3) ^ (q & 7);
                ushort* d = &Ys[q * 128 + blk * 8 + (c0 & 7)];
                *(uint*)d = w0;
                *(uint*)(d + 2) = w1;
            }
        __syncthreads();
        // ---- GEMM2: Z += W x Ys  (m=o 128 split by oH, k=c 128)
#pragma unroll
        for (int ks2 = 0; ks2 < 4; ++ks2) {
            short8 wfa[4];
            const ushort* wb = Wo + (size_t)(oH + l16) * 384 + s * 128 + ks2 * 32 + quad * 8;
#pragma unroll
            for (int ms2 = 0; ms2 < 4; ++ms2)
                wfa[ms2] = *(const short8*)(wb + (size_t)ms2 * 16 * 384);
            short8 b2[2];
#pragma unroll
            for (int ns = 0; ns < 2; ++ns) {
                int q = qH + ns * 16 + l16;
                int blk = (ks2 * 4 + quad) ^ (q & 7);
                b2[ns] = *(const short8*)&Ys[q * 128 + blk * 8];
            }
#pragma unroll
            for (int ms2 = 0; ms2 < 4; ++ms2)
#pragma unroll
                for (int ns = 0; ns < 2; ++ns)
                    acc2[ms2][ns] = __builtin_amdgcn_mfma_f32_16x16x32_bf16(wfa[ms2], b2[ns], acc2[ms2][ns], 0, 0, 0);
        }
    }

    // ---- epilogue: write Z fp32 in pix' order
    float* zp = Z + (size_t)np * 128 * PIX + v * 64;
#pragma unroll
    for (int ms2 = 0; ms2 < 4; ++ms2)
#pragma unroll
        for (int ns = 0; ns < 2; ++ns) {
            int q = qH + ns * 16 + l16;
#pragma unroll
            for (int r = 0; r < 4; ++r) {
                int o = oH + ms2 * 16 + quad * 4 + r;
                zp[(size_t)o * PIX + q] = acc2[ms2][ns][r];
            }
        }
}

// ---------------------------------------------------------------------------
// BN stats + finalize
// ---------------------------------------------------------------------------
__global__ void bn_stats(const float* __restrict__ z, float* __restrict__ stats) {
    const int c = blockIdx.x, np = blockIdx.y, tid = threadIdx.x;
    const float* zp = z + ((size_t)np * CCH + c) * PIX;
    float s = 0.f, s2 = 0.f;
    for (int i = tid; i < PIX; i += 256) {
        float v = zp[i];
        s += v; s2 += v * v;
    }
    for (int off = 32; off; off >>= 1) {
        s += __shfl_down(s, off);
        s2 += __shfl_down(s2, off);
    }
    __shared__ float ls[4], ls2[4];
    const int w = tid >> 6, lane = tid & 63;
    if (lane == 0) { ls[w] = s; ls2[w] = s2; }
    __syncthreads();
    if (tid == 0) {
        s = ls[0] + ls[1] + ls[2] + ls[3];
        s2 = ls2[0] + ls2[1] + ls2[2] + ls2[3];
        atomicAdd(&stats[c], s);
        atomicAdd(&stats[128 + c], s2);
    }
}

__global__ void bn_finalize(const float* __restrict__ stats, const float* __restrict__ g,
                            const float* __restrict__ be, float* __restrict__ scsh) {
    const int c = threadIdx.x;
    float mean = stats[c] * (1.0f / EPC);
    float var = stats[128 + c] * (1.0f / EPC) - mean * mean;
    float inv = rsqrtf(var + 1e-5f);
    float sc = g[c] * inv;
    scsh[c] = sc;
    scsh[128 + c] = be[c] - mean * sc;
}

// ---------------------------------------------------------------------------
// res1: y1 = leaky(x + bn(Z')), fp32 out + bf16 copy (same rounding as before)
// ---------------------------------------------------------------------------
__global__ void res_bn_g(const float* __restrict__ x, const float* __restrict__ z,
                         const float* __restrict__ scsh, float* __restrict__ out,
                         ushort* __restrict__ outb) {
    size_t i = ((size_t)blockIdx.x * 256 + threadIdx.x) * 4;
    size_t row = i / PIX;
    int p = (int)(i % PIX);
    int ch = (int)(row & 127);
    float sc = scsh[ch], sh = scsh[128 + ch];
    const float* zr = z + row * PIX;
    float4 a = *(const float4*)(x + i);
    float xin[4] = {a.x, a.y, a.z, a.w};
    float4 r;
    float ro[4];
#pragma unroll
    for (int j = 0; j < 4; ++j) {
        int pp = p + j;
        int t = pp / 25, vv = pp - t * 25;
        float zz = zr[vv * 64 + t];
        float val = xin[j] + fmaf(zz, sc, sh);
        ro[j] = val >= 0.f ? val : 0.1f * val;
    }
    r.x = ro[0]; r.y = ro[1]; r.z = ro[2]; r.w = ro[3];
    *(float4*)(out + i) = r;
    uint2 ub;
    ub.x = (uint)f2bf(ro[0]) | ((uint)f2bf(ro[1]) << 16);
    ub.y = (uint)f2bf(ro[2]) | ((uint)f2bf(ro[3]) << 16);
    *(uint2*)(outb + i) = ub;
}

// ---------------------------------------------------------------------------
// res2: out = leaky(y1 + bn(z2)), all orig order, float4
// ---------------------------------------------------------------------------
__global__ void res_bn_l(const float4* __restrict__ xr, const float4* __restrict__ zr,
                         const float* __restrict__ scsh, float4* __restrict__ out) {
    int i = blockIdx.x * 256 + threadIdx.x;
    int row = i / 400;
    int ch = row & 127;
    float sc = scsh[ch], sh = scsh[128 + ch];
    float4 a = xr[i], b = zr[i], r;
    r.x = a.x + fmaf(b.x, sc, sh);
    r.y = a.y + fmaf(b.y, sc, sh);
    r.z = a.z + fmaf(b.z, sc, sh);
    r.w = a.w + fmaf(b.w, sc, sh);
    r.x = r.x >= 0.f ? r.x : 0.1f * r.x;
    r.y = r.y >= 0.f ? r.y : 0.1f * r.y;
    r.z = r.z >= 0.f ? r.z : 0.1f * r.z;
    r.w = r.w >= 0.f ? r.w : 0.1f * r.w;
    out[i] = r;
}

// ---------------------------------------------------------------------------
struct Ctx {
    ushort *xr, *Wp, *Wo, *Wf, *ATTQ;
    float *bp;
    float *R1, *R0, *STATS;
    const float *alphat, *b_out, *g_out, *be_out, *b_ff, *g_ff, *be_ff;
};

static void run_block(const float* X, const float* attb, float* OUT,
                      const Ctx& c, hipStream_t stream) {
    const int EG = 38400;   // 39,321,600 / (256*4)
    remap_x<<<EG, 256, 0, stream>>>(X, c.xr);
    // q/k conv -> QK (bf16, in R1), channels [q0|k0|q1|k1|q2|k2]
    gemm_conv<<<dim3(NPB, 13, 3), 256, 0, stream>>>(c.xr, 1, c.Wp, 128, c.bp,
                                                    (void*)c.R1, 1, 192, 0);
    scores_mfma<<<dim3(NPB, 3), 256, 0, stream>>>((const ushort*)c.R1, attb, c.alphat, c.ATTQ);
    // fused attention-apply + output conv (all 3 subsets, all 128 o), Z in R0
    attn_conv<<<dim3(NPB, VV), 256, 0, stream>>>(c.xr, c.ATTQ, c.Wo, c.b_out, c.R0);
    hipMemsetAsync(c.STATS, 0, 256 * sizeof(float), stream);
    bn_stats<<<dim3(CCH, NPB), 256, 0, stream>>>(c.R0, c.STATS);
    bn_finalize<<<1, 128, 0, stream>>>(c.STATS, c.g_out, c.be_out, c.STATS + 256);
    // y1 fp32 in R1, y1 bf16 in xr (xr is dead for the rest of this block)
    res_bn_g<<<EG, 256, 0, stream>>>(X, c.R0, c.STATS + 256, c.R1, c.xr);
    gemm_conv<<<dim3(NPB, 13, 2), 256, 0, stream>>>(c.xr, 1, c.Wf, 128, c.b_ff,
                                                    (void*)c.R0, 0, 128, 0);  // z2 in R0
    hipMemsetAsync(c.STATS, 0, 256 * sizeof(float), stream);
    bn_stats<<<dim3(CCH, NPB), 256, 0, stream>>>(c.R0, c.STATS);
    bn_finalize<<<1, 128, 0, stream>>>(c.STATS, c.g_ff, c.be_ff, c.STATS + 256);
    res_bn_l<<<EG, 256, 0, stream>>>((const float4*)c.R1, (const float4*)c.R0,
                                     c.STATS + 256, (float4*)OUT);
}

extern "C" void kernel_launch(void* const* d_in, const int* in_sizes, int n_in,
                              void* d_out, int out_size, void* d_ws, size_t ws_size,
                              hipStream_t stream) {
    const float* x = (const float*)d_in[0];
    const float* att1 = (const float*)d_in[1];
    const float* att2 = (const float*)d_in[2];
    Ctx c;
    c.alphat = (const float*)d_in[3];
    const float* w_in = (const float*)d_in[4];
    const float* b_in = (const float*)d_in[5];
    const float* w_out = (const float*)d_in[6];
    c.b_out = (const float*)d_in[7];
    c.g_out = (const float*)d_in[8];
    c.be_out = (const float*)d_in[9];
    const float* w_ff = (const float*)d_in[10];
    c.b_ff = (const float*)d_in[11];
    c.g_ff = (const float*)d_in[12];
    c.be_ff = (const float*)d_in[13];

    char* ws = (char*)d_ws;
    size_t off = 0;
    c.xr = (ushort*)(ws + off);   off += ETOT * 2;                    //  78.6 MB
    c.R1 = (float*)(ws + off);    off += ETOT * 4;                    // 157.3 MB
    c.R0 = (float*)(ws + off);    off += ETOT * 4;                    // 157.3 MB
    c.ATTQ = (ushort*)(ws + off); off += (size_t)32 * 3 * 6 * 4096 * 2; // 4.7 MB
    c.STATS = (float*)(ws + off); off += 512 * 4;
    c.Wp = (ushort*)(ws + off);   off += 192 * 128 * 2;
    c.bp = (float*)(ws + off);    off += 192 * 4;
    c.Wo = (ushort*)(ws + off);   off += 128 * 384 * 2;
    c.Wf = (ushort*)(ws + off);   off += 128 * 128 * 2;

    wprep<<<192, 256, 0, stream>>>(w_in, b_in, w_out, w_ff, c.Wp, c.bp, c.Wo, c.Wf);

    float* out = (float*)d_out;
    run_block(x, att1, out, c, stream);
    run_block(out, att2, out, c, stream);
}